// Round 1
// baseline (6469.788 us; speedup 1.0000x reference)
//
#include <hip/hip_runtime.h>
#include <math.h>

#define CH 86
#define SP 54
#define SS2 2916
#define SS3 157464
#define DG 48
#define RT_ROWS (CH*SS2)   /* 250776 rows of (i,x,y) */
#define NSLICE (CH*SP)     /* 4644 */
#define PI_F 3.14159265358979323846f
#define GN_INV (1.0/13541904.0)

static constexpr size_t A512(size_t x){ return (x + 511) & ~((size_t)511); }
static constexpr size_t HBYTES = (size_t)CH*SS3*4;            // 54,167,616
static constexpr size_t FAB = (size_t)CH*SS2*6*8;             // 12,037,248
static constexpr size_t FBB = (size_t)CH*SP*12*6*8;           // 2,674,944
static constexpr size_t FCB = (size_t)CH*864*8;               // 594,432
static constexpr size_t OFF_HA = 0;
static constexpr size_t OFF_HB = OFF_HA + A512(HBYTES);
static constexpr size_t OFF_HS = OFF_HB + A512(HBYTES);
static constexpr size_t OFF_T  = OFF_HS + A512(HBYTES);
static constexpr size_t OFF_FA = OFF_T  + A512(HBYTES);
static constexpr size_t OFF_FB = OFF_FA + A512(FAB);
static constexpr size_t OFF_FC = OFF_FB + A512(FBB);
static constexpr size_t OFF_FD = OFF_FC + A512(FCB);
static constexpr size_t OFF_FE = OFF_FD + A512(FCB);
static constexpr size_t OFF_ST = OFF_FE + A512(FBB);
static constexpr size_t OFF_K3 = OFF_ST + 512;
static constexpr size_t OFF_FY = OFF_K3 + A512((size_t)196608*CH*4);
// total need ~341 MB; GNO chunk buffers overlay hA/hB/hS (dead after build_fy):
static constexpr int    CHUNK_M = 49152;
static constexpr size_t OFF_KIN = 0;
static constexpr size_t OFF_Z1  = A512((size_t)CHUNK_M*96*4);
static constexpr size_t OFF_Z2  = OFF_Z1 + A512((size_t)CHUNK_M*512*4);

__device__ __forceinline__ float gelu_f(float x){
  return 0.5f*x*(1.0f + erff(x*0.70710678118654752440f));
}

__global__ void k_zero_stats(double* st){ if (threadIdx.x < 16) st[threadIdx.x] = 0.0; }

// ---------------- lift + pad ----------------
__global__ __launch_bounds__(256) void k_lift(const float* __restrict__ df,
    const float* __restrict__ wl, const float* __restrict__ bl, float* __restrict__ h)
{
  const int x = blockIdx.x;   // 0..53
  const int o = blockIdx.y;   // 0..85
  float* hp = h + (size_t)o*SS3 + (size_t)x*SS2;
  const int t = threadIdx.x;
  if (x >= DG){
    for(int idx=t; idx<SS2; idx+=256) hp[idx]=0.f;
    return;
  }
  const float w0=wl[o*5], w1=wl[o*5+1], w2=wl[o*5+2], w3=wl[o*5+3], w4=wl[o*5+4];
  const float bo = bl[o];
  const float cx = x*(1.0f/47.0f);
  for(int idx=t; idx<SS2; idx+=256){
    int y = idx/54, z = idx-54*y;
    float v = 0.f;
    if (y<DG && z<DG){
      int p = (x*DG + y)*DG + z;
      float cy = y*(1.0f/47.0f), cz = z*(1.0f/47.0f);
      v = w0*df[p] + w1*df[110592+p] + w2*cx + w3*cy + w4*cz + bo;
    }
    hp[idx] = v;
  }
}

// ---------------- forward partial DFT ----------------
// Stage Z: A[row=(i,x,y)][kz=0..5] complex = sum_z h[row][z] e^{-2pi i kz z/54}
__global__ __launch_bounds__(256) void k_dft_z(const float* __restrict__ h, float* __restrict__ A)
{
  __shared__ alignas(16) float rows[64*55];
  __shared__ float twc[6*54], tws[6*54];
  const int t = threadIdx.x;
  for(int idx=t; idx<6*54; idx+=256){
    int k = idx/54, z = idx-54*k;
    int m = (k*z)%54;
    float ang = -(2.0f*PI_F/54.0f)*(float)m;
    twc[idx]=cosf(ang); tws[idx]=sinf(ang);
  }
  const int r0 = blockIdx.x*64;
  for(int idx=t; idx<64*54; idx+=256){
    int r = idx/54;
    rows[r*55 + (idx-54*r)] = (r0+r < RT_ROWS)? h[(size_t)r0*54 + idx] : 0.f;
  }
  __syncthreads();
  for(int oi=t; oi<768; oi+=256){
    int r = oi & 63;
    int k = (oi>>6)%6;
    int part = oi/384;
    if (r0+r < RT_ROWS){
      const float* tw = part? tws : twc;
      const float* rp = &rows[r*55];
      const float* twk = &tw[k*54];
      float acc=0.f;
      #pragma unroll 6
      for(int z=0;z<54;z++) acc += rp[z]*twk[z];
      A[((size_t)(r0+r)*6 + k)*2 + part] = acc;
    }
  }
}

// Stage Y: B[(i,x)][kyi=0..11][kz] = sum_y A[(i,x)][y][kz] e^{-2pi i ky y/54}, ky = kyi<6?kyi:42+kyi
__global__ __launch_bounds__(256) void k_dft_y(const float* __restrict__ A, float* __restrict__ B)
{
  __shared__ float asl[4*648];
  __shared__ float twc[12*54], tws[12*54];
  const int t = threadIdx.x;
  for(int idx=t; idx<12*54; idx+=256){
    int kyi = idx/54, y = idx-54*kyi;
    int ky = (kyi<6)? kyi : (42+kyi);
    int m = (ky*y)%54;
    float ang = -(2.0f*PI_F/54.0f)*(float)m;
    twc[idx]=cosf(ang); tws[idx]=sinf(ang);
  }
  const int s0 = blockIdx.x*4;
  for(int idx=t; idx<4*648; idx+=256){
    int sl = idx/648;
    asl[idx] = (s0+sl < NSLICE)? A[(size_t)s0*648 + idx] : 0.f;
  }
  __syncthreads();
  for(int oi=t; oi<4*72; oi+=256){
    int sl = oi/72, o = oi-72*sl;
    if (s0+sl >= NSLICE) continue;
    int kyi = o/6, kz = o-6*kyi;
    const float* base = &asl[sl*648];
    float cr=0.f, ci=0.f;
    for(int y=0;y<54;y++){
      float ar = base[(y*6+kz)*2], ai = base[(y*6+kz)*2+1];
      float tc = twc[kyi*54+y], ts = tws[kyi*54+y];
      cr += ar*tc - ai*ts;
      ci += ar*ts + ai*tc;
    }
    size_t ob = ((size_t)(s0+sl)*12 + kyi)*6 + kz;
    B[ob*2]=cr; B[ob*2+1]=ci;
  }
}

// Stage X: C[i][c][f] ; f = ((mx*6+my)*6+kz), c = 2*(kx high)+(ky high)
__global__ __launch_bounds__(256) void k_dft_x(const float* __restrict__ B, float* __restrict__ C)
{
  __shared__ float bsl[7776];
  __shared__ float twc[12*54], tws[12*54];
  const int t = threadIdx.x;
  const int i = blockIdx.x;
  for(int idx=t; idx<12*54; idx+=256){
    int kxi = idx/54, x = idx-54*kxi;
    int kx = (kxi<6)? kxi : (42+kxi);
    int m = (kx*x)%54;
    float ang = -(2.0f*PI_F/54.0f)*(float)m;
    twc[idx]=cosf(ang); tws[idx]=sinf(ang);
  }
  for(int idx=t; idx<7776; idx+=256) bsl[idx] = B[(size_t)i*7776 + idx];
  __syncthreads();
  for(int oi=t; oi<864; oi+=256){
    int kxi = oi/72, rest = oi-72*kxi;
    float cr=0.f, ci=0.f;
    for(int x=0;x<54;x++){
      float br = bsl[(x*72+rest)*2], bi = bsl[(x*72+rest)*2+1];
      float tc = twc[kxi*54+x], ts = tws[kxi*54+x];
      cr += br*tc - bi*ts;
      ci += br*ts + bi*tc;
    }
    int kyi = rest/6, kz = rest-6*kyi;
    int c = ((kxi>=6)?2:0) + ((kyi>=6)?1:0);
    int f = ((kxi%6)*6 + (kyi%6))*6 + kz;
    size_t ob = ((size_t)i*4 + c)*216 + f;
    C[ob*2]=cr; C[ob*2+1]=ci;
  }
}

// Mixing: D[o][kxi][kyi][kz] = sum_i C[i][c][f] * (wr + i wi)[c][i][o][f]
__global__ __launch_bounds__(256) void k_mix(const float* __restrict__ C,
    const float* __restrict__ wr, const float* __restrict__ wi, float* __restrict__ D)
{
  const int f = threadIdx.x;
  if (f >= 216) return;
  const int o = blockIdx.x, c = blockIdx.y;
  const size_t wstride = (size_t)CH*216;
  const float* wrp = wr + ((size_t)c*CH*CH + o)*216 + f;
  const float* wip = wi + ((size_t)c*CH*CH + o)*216 + f;
  const float* cp  = C + ((size_t)c*216 + f)*2;
  float ar=0.f, ai=0.f;
  #pragma unroll 4
  for(int i=0;i<CH;i++){
    float cr = cp[0], cim = cp[1];
    float xr = *wrp, xi = *wip;
    ar += cr*xr - cim*xi;
    ai += cr*xi + cim*xr;
    wrp += wstride; wip += wstride;
    cp += 864*2;
  }
  int mx = f/36, my = (f/6)%6, kz = f%6;
  int kxi = mx + ((c>=2)?6:0);
  int kyi = my + ((c&1)?6:0);
  size_t ob = (((size_t)o*12 + kxi)*12 + kyi)*6 + kz;
  D[ob*2]=ar; D[ob*2+1]=ai;
}

// ---------------- inverse partial DFT ----------------
__global__ __launch_bounds__(256) void k_idft_x(const float* __restrict__ D, float* __restrict__ E)
{
  __shared__ float dsl[1728];
  __shared__ float twc[12*54], tws[12*54];
  const int t = threadIdx.x;
  const int o = blockIdx.x;
  for(int idx=t; idx<12*54; idx+=256){
    int kxi = idx/54, x = idx-54*kxi;
    int kx = (kxi<6)? kxi : (42+kxi);
    int m = (kx*x)%54;
    float ang = (2.0f*PI_F/54.0f)*(float)m;
    twc[idx]=cosf(ang); tws[idx]=sinf(ang);
  }
  for(int idx=t; idx<1728; idx+=256) dsl[idx] = D[(size_t)o*1728 + idx];
  __syncthreads();
  for(int oi=t; oi<3888; oi+=256){
    int x = oi/72, rest = oi-72*x;
    float er=0.f, ei=0.f;
    #pragma unroll
    for(int kxi=0;kxi<12;kxi++){
      float dr = dsl[(kxi*72+rest)*2], di = dsl[(kxi*72+rest)*2+1];
      float tc = twc[kxi*54+x], ts = tws[kxi*54+x];
      er += dr*tc - di*ts;
      ei += dr*ts + di*tc;
    }
    size_t ob = (size_t)o*3888 + oi;
    E[ob*2]=er; E[ob*2+1]=ei;
  }
}

__global__ __launch_bounds__(256) void k_idft_y(const float* __restrict__ E, float* __restrict__ F)
{
  __shared__ float esl[4*144];
  __shared__ float twc[12*54], tws[12*54];
  const int t = threadIdx.x;
  for(int idx=t; idx<12*54; idx+=256){
    int kyi = idx/54, y = idx-54*kyi;
    int ky = (kyi<6)? kyi : (42+kyi);
    int m = (ky*y)%54;
    float ang = (2.0f*PI_F/54.0f)*(float)m;
    twc[idx]=cosf(ang); tws[idx]=sinf(ang);
  }
  const int s0 = blockIdx.x*4;
  for(int idx=t; idx<4*144; idx+=256){
    int sl = idx/144;
    esl[idx] = (s0+sl < NSLICE)? E[(size_t)s0*144 + idx] : 0.f;
  }
  __syncthreads();
  for(int oi=t; oi<4*324; oi+=256){
    int sl = oi/324, rest = oi-324*sl;
    if (s0+sl >= NSLICE) continue;
    int y = rest/6, kz = rest-6*y;
    const float* base = &esl[sl*144];
    float fr=0.f, fi=0.f;
    #pragma unroll
    for(int kyi=0;kyi<12;kyi++){
      float er = base[(kyi*6+kz)*2], ei = base[(kyi*6+kz)*2+1];
      float tc = twc[kyi*54+y], ts = tws[kyi*54+y];
      fr += er*tc - ei*ts;
      fi += er*ts + ei*tc;
    }
    size_t ob = ((size_t)(s0+sl)*54 + y)*6 + kz;
    F[ob*2]=fr; F[ob*2+1]=fi;
  }
}

// Stage Z': real synthesis (irfft: Im of bin0 dropped), *1/54^3, + global sum/sumsq
__global__ __launch_bounds__(256) void k_idft_z(const float* __restrict__ F,
    float* __restrict__ hs, double* __restrict__ st)
{
  __shared__ float rws[64*12];
  __shared__ float twc[5*54], tws[5*54];
  __shared__ float red[8];
  const int t = threadIdx.x;
  for(int idx=t; idx<5*54; idx+=256){
    int k = idx/54 + 1, z = idx%54;
    int m = (k*z)%54;
    float ang = (2.0f*PI_F/54.0f)*(float)m;
    twc[idx]=cosf(ang); tws[idx]=sinf(ang);
  }
  const int r0 = blockIdx.x*64;
  for(int idx=t; idx<768; idx+=256){
    int r = idx/12;
    rws[idx] = (r0+r < RT_ROWS)? F[(size_t)r0*12 + idx] : 0.f;
  }
  __syncthreads();
  const float inv = 1.0f/157464.0f;
  float lsum=0.f, lsq=0.f;
  for(int oi=t; oi<64*54; oi+=256){
    int r = oi/54, z = oi-54*r;
    if (r0+r < RT_ROWS){
      const float* fr = &rws[r*12];
      float acc = fr[0];
      #pragma unroll
      for(int k=1;k<=5;k++)
        acc += 2.0f*(fr[2*k]*twc[(k-1)*54+z] - fr[2*k+1]*tws[(k-1)*54+z]);
      acc *= inv;
      hs[(size_t)r0*54 + oi] = acc;
      lsum += acc; lsq += acc*acc;
    }
  }
  #pragma unroll
  for(int off=32; off; off>>=1){
    lsum += __shfl_down(lsum, off, 64);
    lsq  += __shfl_down(lsq,  off, 64);
  }
  if ((t&63)==0){ red[(t>>6)*2]=lsum; red[(t>>6)*2+1]=lsq; }
  __syncthreads();
  if (t==0){
    double s1 = (double)red[0]+red[2]+red[4]+red[6];
    double s2 = (double)red[1]+red[3]+red[5]+red[7];
    atomicAdd(st, s1); atomicAdd(st+1, s2);
  }
}

// ---------------- 1x1 conv (86->86), optional fused norm-add / gelu / out-stats ----------------
template<int ACT, int ADDN, int OSTAT>
__global__ __launch_bounds__(256,2) void k_conv86(
    const float* __restrict__ in, const float* __restrict__ W,
    const float* __restrict__ bias, const float* __restrict__ X,
    const float* __restrict__ g, const float* __restrict__ bg,
    const double* __restrict__ ist, double* __restrict__ ost,
    float* __restrict__ out)
{
  __shared__ alignas(16) float tin[CH*128];
  __shared__ alignas(16) float wt[32*96];
  __shared__ float red[8];
  const int t = threadIdx.x;
  const int s0 = blockIdx.x*128;
  for(int idx=t; idx<CH*128; idx+=256){
    int i = idx>>7, sp = idx&127;
    int s = s0+sp;
    tin[idx] = (s<SS3)? in[i*SS3 + s] : 0.f;
  }
  const int sg = t&31, rowq = t>>5;  // o = rowq*11 + j
  float acc[11][4];
  #pragma unroll
  for(int j=0;j<11;j++){acc[j][0]=0.f;acc[j][1]=0.f;acc[j][2]=0.f;acc[j][3]=0.f;}
  int c0 = 0;
  for(int chunk=0; chunk<3; chunk++){
    int cnt = (chunk<2)? 32 : 22;
    __syncthreads();
    for(int idx=t; idx<CH*cnt; idx+=256){
      int o = idx/cnt, ic = idx - o*cnt;
      wt[ic*96 + (o/11)*12 + (o%11)] = W[o*CH + c0 + ic];
    }
    __syncthreads();
    #pragma unroll 2
    for(int ii=0; ii<cnt; ii++){
      const float4 a = *reinterpret_cast<const float4*>(&tin[(c0+ii)*128 + sg*4]);
      const float4* wv = reinterpret_cast<const float4*>(&wt[ii*96 + rowq*12]);
      const float4 w0 = wv[0], w1 = wv[1], w2 = wv[2];
      const float wj[12] = {w0.x,w0.y,w0.z,w0.w,w1.x,w1.y,w1.z,w1.w,w2.x,w2.y,w2.z,w2.w};
      #pragma unroll
      for(int j=0;j<11;j++){
        acc[j][0] += wj[j]*a.x;
        acc[j][1] += wj[j]*a.y;
        acc[j][2] += wj[j]*a.z;
        acc[j][3] += wj[j]*a.w;
      }
    }
    c0 += cnt;
  }
  float mu=0.f, rs=1.f;
  if (ADDN){
    double m = ist[0]*GN_INV;
    double v = ist[1]*GN_INV - m*m;
    mu = (float)m;
    rs = (float)(1.0/sqrt(v + 1e-5));
  }
  float lsum=0.f, lsq=0.f;
  #pragma unroll
  for(int j=0;j<11;j++){
    int o = rowq*11 + j;
    if (o < CH){
      float bo = bias[o];
      float gg=1.f, bb=0.f;
      if (ADDN){ gg = g[o]; bb = bg[o]; }
      #pragma unroll
      for(int e=0;e<4;e++){
        int s = s0 + sg*4 + e;
        if (s < SS3){
          float v = acc[j][e] + bo;
          if (ADDN) v += (X[o*SS3 + s]-mu)*rs*gg + bb;
          if (ACT) v = gelu_f(v);
          if (OSTAT){ lsum += v; lsq += v*v; }
          out[o*SS3 + s] = v;
        }
      }
    }
  }
  if (OSTAT){
    #pragma unroll
    for(int off=32; off; off>>=1){
      lsum += __shfl_down(lsum, off, 64);
      lsq  += __shfl_down(lsq,  off, 64);
    }
    if ((t&63)==0){ red[(t>>6)*2]=lsum; red[(t>>6)*2+1]=lsq; }
    __syncthreads();
    if (t==0){
      double s1 = (double)red[0]+red[2]+red[4]+red[6];
      double s2 = (double)red[1]+red[3]+red[5]+red[7];
      atomicAdd(ost, s1); atomicAdd(ost+1, s2);
    }
  }
}

// ---------------- f_y: crop + transpose to [p][c] ----------------
__global__ __launch_bounds__(256) void k_build_fy(const float* __restrict__ h, float* __restrict__ fy)
{
  __shared__ float tile[CH*49];
  const int b = blockIdx.x;       // 0..2303
  const int x = b/48, y = b-48*x;
  const int t = threadIdx.x;
  for(int idx=t; idx<CH*48; idx+=256){
    int c = idx/48, z = idx-48*c;
    tile[c*49+z] = h[(size_t)c*SS3 + x*SS2 + y*54 + z];
  }
  __syncthreads();
  const size_t p0 = ((size_t)x*48 + y)*48;
  for(int idx=t; idx<48*CH; idx+=256){
    int z = idx/CH, c = idx-CH*z;
    fy[(p0+z)*CH + c] = tile[c*49+z];
  }
}

// ---------------- kin: [pair][96] = [y-embed(48) | q-embed(48)] ----------------
__global__ __launch_bounds__(256) void k_build_kin(const float* __restrict__ x_in,
    const int* __restrict__ nb_idx, float* __restrict__ kin, int pair0)
{
  int gidx = blockIdx.x*256 + threadIdx.x;
  int lp = gidx/96, col = gidx - lp*96;
  int pair = pair0 + lp;
  int qi = pair/24;
  int cc = col; bool isq = false;
  if (cc >= 48){ cc -= 48; isq = true; }
  int ci = cc>>4, e = cc&15;
  int f = e&7; bool is_sin = (e>=8);
  float coord;
  if (isq){
    coord = x_in[qi*3 + ci];
  } else {
    int pt = nb_idx[pair];
    int gcoord;
    if (ci==0) gcoord = pt/2304;
    else if (ci==1) gcoord = (pt/48)%48;
    else gcoord = pt%48;
    coord = gcoord*(1.0f/47.0f);
  }
  float freq = exp2f(-(float)f * 1.66096404744368117f);  // 10000^{-f/8}
  float ang = coord*freq;
  kin[gidx] = is_sin ? sinf(ang) : cosf(ang);
}

// ---------------- GEMM: C[m][n] = act(sum_k A[m][k]*B[n][k] + bias[n]) ----------------
template<int ACT>
__global__ __launch_bounds__(256,2) void k_gemm_tn(
    const float* __restrict__ A, const float* __restrict__ B,
    const float* __restrict__ bias, float* __restrict__ C,
    int M, int N, int K)
{
  __shared__ alignas(16) float As[32*132];
  __shared__ alignas(16) float Bs[32*68];
  const int t = threadIdx.x;
  const int m0 = blockIdx.x*128;
  const int n0 = blockIdx.y*64;
  const int mg = t>>4, ng = t&15;
  float acc[8][4];
  #pragma unroll
  for(int r=0;r<8;r++){
    #pragma unroll
    for(int c=0;c<4;c++) acc[r][c]=0.f;
  }
  for(int k0=0;k0<K;k0+=32){
    #pragma unroll
    for(int j=0;j<16;j++){
      int idx = j*256+t;
      int m = idx>>5, k = idx&31;
      As[k*132+m] = A[(m0+m)*K + (k0+k)];
    }
    #pragma unroll
    for(int j=0;j<8;j++){
      int idx = j*256+t;
      int n = idx>>5, k = idx&31;
      Bs[k*68+n] = (n0+n < N)? B[(n0+n)*K + (k0+k)] : 0.f;
    }
    __syncthreads();
    #pragma unroll
    for(int k=0;k<32;k++){
      const float4 a0 = *reinterpret_cast<const float4*>(&As[k*132 + mg*8]);
      const float4 a1 = *reinterpret_cast<const float4*>(&As[k*132 + mg*8 + 4]);
      const float4 b  = *reinterpret_cast<const float4*>(&Bs[k*68 + ng*4]);
      const float av[8] = {a0.x,a0.y,a0.z,a0.w,a1.x,a1.y,a1.z,a1.w};
      const float bv[4] = {b.x,b.y,b.z,b.w};
      #pragma unroll
      for(int r=0;r<8;r++){
        #pragma unroll
        for(int c=0;c<4;c++) acc[r][c] += av[r]*bv[c];
      }
    }
    __syncthreads();
  }
  #pragma unroll
  for(int r=0;r<8;r++){
    int m = m0 + mg*8 + r;
    #pragma unroll
    for(int c=0;c<4;c++){
      int n = n0 + ng*4 + c;
      if (n < N){
        float v = acc[r][c] + bias[n];
        if (ACT) v = gelu_f(v);
        C[(size_t)m*N + n] = v;
      }
    }
  }
}

// ---------------- GNO reduce + projection head ----------------
__global__ __launch_bounds__(256) void k_gno_reduce(
    const float* __restrict__ K3, const float* __restrict__ fy,
    const int* __restrict__ nb_idx, const int* __restrict__ nb_mask,
    const float* __restrict__ p1w, const float* __restrict__ p1b,
    const float* __restrict__ p2w, const float* __restrict__ p2b,
    float* __restrict__ out)
{
  __shared__ float v[CH];
  __shared__ int   sidx[24];
  __shared__ float smk[24];
  __shared__ float red[4];
  const int i = blockIdx.x, t = threadIdx.x;
  if (t < 24){
    sidx[t] = nb_idx[i*24+t];
    smk[t]  = (nb_mask[i*24+t] != 0)? 1.f : 0.f;
  }
  __syncthreads();
  if (t < CH){
    float acc=0.f, den=0.f;
    for(int k=0;k<24;k++){
      float m = smk[k];
      den += m;
      if (m > 0.f)
        acc += K3[((size_t)(i*24+k))*CH + t]*fy[(size_t)sidx[k]*CH + t];
    }
    if (den < 1.f) den = 1.f;
    v[t] = acc/den;
  }
  __syncthreads();
  float a1 = p1b[t];
  for(int c=0;c<CH;c++) a1 += v[c]*p1w[t*CH + c];
  float part = gelu_f(a1)*p2w[t];
  #pragma unroll
  for(int off=32; off; off>>=1) part += __shfl_down(part, off, 64);
  if ((t&63)==0) red[t>>6] = part;
  __syncthreads();
  if (t==0) out[i] = red[0]+red[1]+red[2]+red[3] + p2b[0];
}

// ---------------- launch ----------------
extern "C" void kernel_launch(void* const* d_in, const int* in_sizes, int n_in,
                              void* d_out, int out_size, void* d_ws, size_t ws_size,
                              hipStream_t stream)
{
  (void)in_sizes; (void)n_in; (void)out_size; (void)ws_size;
  const float* x_in  = (const float*)d_in[0];
  const float* df    = (const float*)d_in[2];
  const int*   nbidx = (const int*)d_in[3];
  const int*   nbmsk = (const int*)d_in[4];
  const float* wlift = (const float*)d_in[5];
  const float* blift = (const float*)d_in[6];
  const float* spwr  = (const float*)d_in[7];
  const float* spwi  = (const float*)d_in[8];
  const float* wskip = (const float*)d_in[9];
  const float* bskip = (const float*)d_in[10];
  const float* m1w   = (const float*)d_in[11];
  const float* m1b   = (const float*)d_in[12];
  const float* m2w   = (const float*)d_in[13];
  const float* m2b   = (const float*)d_in[14];
  const float* wms   = (const float*)d_in[15];
  const float* bms   = (const float*)d_in[16];
  const float* g1w   = (const float*)d_in[17];
  const float* g1b   = (const float*)d_in[18];
  const float* g2w   = (const float*)d_in[19];
  const float* g2b   = (const float*)d_in[20];
  const float* k1w   = (const float*)d_in[21];
  const float* k1b   = (const float*)d_in[22];
  const float* k2w   = (const float*)d_in[23];
  const float* k2b   = (const float*)d_in[24];
  const float* k3w   = (const float*)d_in[25];
  const float* k3b   = (const float*)d_in[26];
  const float* p1w   = (const float*)d_in[27];
  const float* p1b   = (const float*)d_in[28];
  const float* p2w   = (const float*)d_in[29];
  const float* p2b   = (const float*)d_in[30];
  float* out = (float*)d_out;
  char* ws = (char*)d_ws;

  float* hA = (float*)(ws + OFF_HA);
  float* hB = (float*)(ws + OFF_HB);
  float* hS = (float*)(ws + OFF_HS);
  float* tB = (float*)(ws + OFF_T);
  float* fA = (float*)(ws + OFF_FA);
  float* fB = (float*)(ws + OFF_FB);
  float* fC = (float*)(ws + OFF_FC);
  float* fD = (float*)(ws + OFF_FD);
  float* fE = (float*)(ws + OFF_FE);
  double* st= (double*)(ws + OFF_ST);
  float* K3 = (float*)(ws + OFF_K3);
  float* fy = (float*)(ws + OFF_FY);
  float* kin= (float*)(ws + OFF_KIN);
  float* Z1 = (float*)(ws + OFF_Z1);
  float* Z2 = (float*)(ws + OFF_Z2);

  k_zero_stats<<<1,64,0,stream>>>(st);
  k_lift<<<dim3(54,86),256,0,stream>>>(df, wlift, blift, hA);

  for(int l=0;l<4;l++){
    const float* wr_l = spwr + (size_t)l*4*CH*CH*216;
    const float* wi_l = spwi + (size_t)l*4*CH*CH*216;
    double* st1 = st + l*4;
    double* st2 = st + l*4 + 2;
    k_dft_z<<<3919,256,0,stream>>>(hA, fA);
    k_dft_y<<<1161,256,0,stream>>>(fA, fB);
    k_dft_x<<<86,256,0,stream>>>(fB, fC);
    k_mix<<<dim3(86,4),256,0,stream>>>(fC, wr_l, wi_l, fD);
    k_idft_x<<<86,256,0,stream>>>(fD, fE);
    k_idft_y<<<1161,256,0,stream>>>(fE, fA);
    k_idft_z<<<3919,256,0,stream>>>(fA, hS, st1);
    // h1 = act(gn1(hS) + conv(hA,wskip)) -> hB
    if (l<3) k_conv86<1,1,0><<<1231,256,0,stream>>>(hA, wskip+l*7396, bskip+l*86, hS, g1w+l*86, g1b+l*86, st1, nullptr, hB);
    else     k_conv86<0,1,0><<<1231,256,0,stream>>>(hA, wskip+l*7396, bskip+l*86, hS, g1w+l*86, g1b+l*86, st1, nullptr, hB);
    // t = gelu(conv(hB,m1))
    k_conv86<1,0,0><<<1231,256,0,stream>>>(hB, m1w+l*7396, m1b+l*86, nullptr, nullptr, nullptr, nullptr, nullptr, tB);
    // hm = conv(tB,m2) -> hS (+stats2)
    k_conv86<0,0,1><<<1231,256,0,stream>>>(tB, m2w+l*7396, m2b+l*86, nullptr, nullptr, nullptr, nullptr, st2, hS);
    // h = act(gn2(hS) + conv(hB,wms)) -> hA
    if (l<3) k_conv86<1,1,0><<<1231,256,0,stream>>>(hB, wms+l*7396, bms+l*86, hS, g2w+l*86, g2b+l*86, st2, nullptr, hA);
    else     k_conv86<0,1,0><<<1231,256,0,stream>>>(hB, wms+l*7396, bms+l*86, hS, g2w+l*86, g2b+l*86, st2, nullptr, hA);
  }

  k_build_fy<<<2304,256,0,stream>>>(hA, fy);

  for(int ch=0; ch<4; ch++){
    int pair0 = ch*CHUNK_M;
    k_build_kin<<<(CHUNK_M*96)/256,256,0,stream>>>(x_in, nbidx, kin, pair0);
    k_gemm_tn<1><<<dim3(CHUNK_M/128,8),256,0,stream>>>(kin, k1w, k1b, Z1, CHUNK_M, 512, 96);
    k_gemm_tn<1><<<dim3(CHUNK_M/128,4),256,0,stream>>>(Z1, k2w, k2b, Z2, CHUNK_M, 256, 512);
    k_gemm_tn<0><<<dim3(CHUNK_M/128,2),256,0,stream>>>(Z2, k3w, k3b, K3 + (size_t)pair0*CH, CHUNK_M, 86, 256);
  }

  k_gno_reduce<<<8192,256,0,stream>>>(K3, fy, nbidx, nbmsk, p1w, p1b, p2w, p2b, out);
}

// Round 2
// 3533.712 us; speedup vs baseline: 1.8309x; 1.8309x over previous
//
#include <hip/hip_runtime.h>
#include <math.h>

#define CH 86
#define SP 54
#define SS2 2916
#define SS3 157464
#define DG 48
#define RT_ROWS (CH*SS2)   /* 250776 rows of (i,x,y) */
#define NSLICE (CH*SP)     /* 4644 */
#define PI_F 3.14159265358979323846f
#define GN_INV (1.0/13541904.0)

static constexpr size_t A512(size_t x){ return (x + 511) & ~((size_t)511); }
static constexpr size_t HBYTES = (size_t)CH*SS3*4;            // 54,167,616
static constexpr size_t FAB = (size_t)CH*SS2*6*8;             // 12,037,248
static constexpr size_t FBB = (size_t)CH*SP*12*6*8;           // 2,674,944
static constexpr size_t FCB = (size_t)CH*864*8;               // 594,432
static constexpr size_t OFF_HA = 0;
static constexpr size_t OFF_HB = OFF_HA + A512(HBYTES);
static constexpr size_t OFF_HS = OFF_HB + A512(HBYTES);
static constexpr size_t OFF_T  = OFF_HS + A512(HBYTES);
static constexpr size_t OFF_FA = OFF_T  + A512(HBYTES);
static constexpr size_t OFF_FB = OFF_FA + A512(FAB);
static constexpr size_t OFF_FC = OFF_FB + A512(FBB);
static constexpr size_t OFF_FD = OFF_FC + A512(FCB);
static constexpr size_t OFF_FE = OFF_FD + A512(FCB);
static constexpr size_t OFF_ST = OFF_FE + A512(FBB);
static constexpr size_t OFF_K3 = OFF_ST + 512;
static constexpr size_t OFF_FY = OFF_K3 + A512((size_t)196608*CH*4);
// GNO chunk buffers overlay hA..fE (dead after build_fy). 2 chunks of 98304 pairs.
static constexpr int    CHUNK_M = 98304;
static constexpr size_t OFF_KIN = 0;                                    // bf16 CHUNK*96
static constexpr size_t OFF_Z1  = A512((size_t)CHUNK_M*96*2);           // bf16 CHUNK*512
static constexpr size_t OFF_Z2  = OFF_Z1 + A512((size_t)CHUNK_M*512*2); // bf16 CHUNK*256
static constexpr size_t OFF_W1  = OFF_Z2 + A512((size_t)CHUNK_M*256*2); // bf16 512*96
static constexpr size_t OFF_W2  = OFF_W1 + A512((size_t)512*96*2);      // bf16 256*512
static constexpr size_t OFF_W3  = OFF_W2 + A512((size_t)256*512*2);     // bf16 86*256

typedef __attribute__((ext_vector_type(8))) short bf16x8;
typedef __attribute__((ext_vector_type(4))) float f32x4;

__device__ __forceinline__ float gelu_f(float x){
  return 0.5f*x*(1.0f + erff(x*0.70710678118654752440f));
}
__device__ __forceinline__ unsigned short f2bf(float x){
  unsigned u = __float_as_uint(x);
  u += 0x7fffu + ((u>>16)&1u);
  return (unsigned short)(u>>16);
}

__global__ void k_zero_stats(double* st){ if (threadIdx.x < 16) st[threadIdx.x] = 0.0; }

__global__ __launch_bounds__(256) void k_f2bf(const float* __restrict__ in,
    unsigned short* __restrict__ out, int n)
{
  int i = blockIdx.x*256 + threadIdx.x;
  if (i < n) out[i] = f2bf(in[i]);
}

// ---------------- lift + pad ----------------
__global__ __launch_bounds__(256) void k_lift(const float* __restrict__ df,
    const float* __restrict__ wl, const float* __restrict__ bl, float* __restrict__ h)
{
  const int x = blockIdx.x;   // 0..53
  const int o = blockIdx.y;   // 0..85
  float* hp = h + (size_t)o*SS3 + (size_t)x*SS2;
  const int t = threadIdx.x;
  if (x >= DG){
    for(int idx=t; idx<SS2; idx+=256) hp[idx]=0.f;
    return;
  }
  const float w0=wl[o*5], w1=wl[o*5+1], w2=wl[o*5+2], w3=wl[o*5+3], w4=wl[o*5+4];
  const float bo = bl[o];
  const float cx = x*(1.0f/47.0f);
  for(int idx=t; idx<SS2; idx+=256){
    int y = idx/54, z = idx-54*y;
    float v = 0.f;
    if (y<DG && z<DG){
      int p = (x*DG + y)*DG + z;
      float cy = y*(1.0f/47.0f), cz = z*(1.0f/47.0f);
      v = w0*df[p] + w1*df[110592+p] + w2*cx + w3*cy + w4*cz + bo;
    }
    hp[idx] = v;
  }
}

// ---------------- forward partial DFT ----------------
__global__ __launch_bounds__(256) void k_dft_z(const float* __restrict__ h, float* __restrict__ A)
{
  __shared__ alignas(16) float rows[64*55];
  __shared__ float twc[6*54], tws[6*54];
  const int t = threadIdx.x;
  for(int idx=t; idx<6*54; idx+=256){
    int k = idx/54, z = idx-54*k;
    int m = (k*z)%54;
    float ang = -(2.0f*PI_F/54.0f)*(float)m;
    twc[idx]=cosf(ang); tws[idx]=sinf(ang);
  }
  const int r0 = blockIdx.x*64;
  for(int idx=t; idx<64*54; idx+=256){
    int r = idx/54;
    rows[r*55 + (idx-54*r)] = (r0+r < RT_ROWS)? h[(size_t)r0*54 + idx] : 0.f;
  }
  __syncthreads();
  for(int oi=t; oi<768; oi+=256){
    int r = oi & 63;
    int k = (oi>>6)%6;
    int part = oi/384;
    if (r0+r < RT_ROWS){
      const float* tw = part? tws : twc;
      const float* rp = &rows[r*55];
      const float* twk = &tw[k*54];
      float acc=0.f;
      #pragma unroll 6
      for(int z=0;z<54;z++) acc += rp[z]*twk[z];
      A[((size_t)(r0+r)*6 + k)*2 + part] = acc;
    }
  }
}

__global__ __launch_bounds__(256) void k_dft_y(const float* __restrict__ A, float* __restrict__ B)
{
  __shared__ float asl[4*648];
  __shared__ float twc[12*54], tws[12*54];
  const int t = threadIdx.x;
  for(int idx=t; idx<12*54; idx+=256){
    int kyi = idx/54, y = idx-54*kyi;
    int ky = (kyi<6)? kyi : (42+kyi);
    int m = (ky*y)%54;
    float ang = -(2.0f*PI_F/54.0f)*(float)m;
    twc[idx]=cosf(ang); tws[idx]=sinf(ang);
  }
  const int s0 = blockIdx.x*4;
  for(int idx=t; idx<4*648; idx+=256){
    int sl = idx/648;
    asl[idx] = (s0+sl < NSLICE)? A[(size_t)s0*648 + idx] : 0.f;
  }
  __syncthreads();
  for(int oi=t; oi<4*72; oi+=256){
    int sl = oi/72, o = oi-72*sl;
    if (s0+sl >= NSLICE) continue;
    int kyi = o/6, kz = o-6*kyi;
    const float* base = &asl[sl*648];
    float cr=0.f, ci=0.f;
    for(int y=0;y<54;y++){
      float ar = base[(y*6+kz)*2], ai = base[(y*6+kz)*2+1];
      float tc = twc[kyi*54+y], ts = tws[kyi*54+y];
      cr += ar*tc - ai*ts;
      ci += ar*ts + ai*tc;
    }
    size_t ob = ((size_t)(s0+sl)*12 + kyi)*6 + kz;
    B[ob*2]=cr; B[ob*2+1]=ci;
  }
}

__global__ __launch_bounds__(256) void k_dft_x(const float* __restrict__ B, float* __restrict__ C)
{
  __shared__ float bsl[7776];
  __shared__ float twc[12*54], tws[12*54];
  const int t = threadIdx.x;
  const int i = blockIdx.x;
  for(int idx=t; idx<12*54; idx+=256){
    int kxi = idx/54, x = idx-54*kxi;
    int kx = (kxi<6)? kxi : (42+kxi);
    int m = (kx*x)%54;
    float ang = -(2.0f*PI_F/54.0f)*(float)m;
    twc[idx]=cosf(ang); tws[idx]=sinf(ang);
  }
  for(int idx=t; idx<7776; idx+=256) bsl[idx] = B[(size_t)i*7776 + idx];
  __syncthreads();
  for(int oi=t; oi<864; oi+=256){
    int kxi = oi/72, rest = oi-72*kxi;
    float cr=0.f, ci=0.f;
    for(int x=0;x<54;x++){
      float br = bsl[(x*72+rest)*2], bi = bsl[(x*72+rest)*2+1];
      float tc = twc[kxi*54+x], ts = tws[kxi*54+x];
      cr += br*tc - bi*ts;
      ci += br*ts + bi*tc;
    }
    int kyi = rest/6, kz = rest-6*kyi;
    int c = ((kxi>=6)?2:0) + ((kyi>=6)?1:0);
    int f = ((kxi%6)*6 + (kyi%6))*6 + kz;
    size_t ob = ((size_t)i*4 + c)*216 + f;
    C[ob*2]=cr; C[ob*2+1]=ci;
  }
}

__global__ __launch_bounds__(256) void k_mix(const float* __restrict__ C,
    const float* __restrict__ wr, const float* __restrict__ wi, float* __restrict__ D)
{
  const int f = threadIdx.x;
  if (f >= 216) return;
  const int o = blockIdx.x, c = blockIdx.y;
  const size_t wstride = (size_t)CH*216;
  const float* wrp = wr + ((size_t)c*CH*CH + o)*216 + f;
  const float* wip = wi + ((size_t)c*CH*CH + o)*216 + f;
  const float* cp  = C + ((size_t)c*216 + f)*2;
  float ar=0.f, ai=0.f;
  #pragma unroll 4
  for(int i=0;i<CH;i++){
    float cr = cp[0], cim = cp[1];
    float xr = *wrp, xi = *wip;
    ar += cr*xr - cim*xi;
    ai += cr*xi + cim*xr;
    wrp += wstride; wip += wstride;
    cp += 864*2;
  }
  int mx = f/36, my = (f/6)%6, kz = f%6;
  int kxi = mx + ((c>=2)?6:0);
  int kyi = my + ((c&1)?6:0);
  size_t ob = (((size_t)o*12 + kxi)*12 + kyi)*6 + kz;
  D[ob*2]=ar; D[ob*2+1]=ai;
}

// ---------------- inverse partial DFT ----------------
__global__ __launch_bounds__(256) void k_idft_x(const float* __restrict__ D, float* __restrict__ E)
{
  __shared__ float dsl[1728];
  __shared__ float twc[12*54], tws[12*54];
  const int t = threadIdx.x;
  const int o = blockIdx.x;
  for(int idx=t; idx<12*54; idx+=256){
    int kxi = idx/54, x = idx-54*kxi;
    int kx = (kxi<6)? kxi : (42+kxi);
    int m = (kx*x)%54;
    float ang = (2.0f*PI_F/54.0f)*(float)m;
    twc[idx]=cosf(ang); tws[idx]=sinf(ang);
  }
  for(int idx=t; idx<1728; idx+=256) dsl[idx] = D[(size_t)o*1728 + idx];
  __syncthreads();
  for(int oi=t; oi<3888; oi+=256){
    int x = oi/72, rest = oi-72*x;
    float er=0.f, ei=0.f;
    #pragma unroll
    for(int kxi=0;kxi<12;kxi++){
      float dr = dsl[(kxi*72+rest)*2], di = dsl[(kxi*72+rest)*2+1];
      float tc = twc[kxi*54+x], ts = tws[kxi*54+x];
      er += dr*tc - di*ts;
      ei += dr*ts + di*tc;
    }
    size_t ob = (size_t)o*3888 + oi;
    E[ob*2]=er; E[ob*2+1]=ei;
  }
}

__global__ __launch_bounds__(256) void k_idft_y(const float* __restrict__ E, float* __restrict__ F)
{
  __shared__ float esl[4*144];
  __shared__ float twc[12*54], tws[12*54];
  const int t = threadIdx.x;
  for(int idx=t; idx<12*54; idx+=256){
    int kyi = idx/54, y = idx-54*kyi;
    int ky = (kyi<6)? kyi : (42+kyi);
    int m = (ky*y)%54;
    float ang = (2.0f*PI_F/54.0f)*(float)m;
    twc[idx]=cosf(ang); tws[idx]=sinf(ang);
  }
  const int s0 = blockIdx.x*4;
  for(int idx=t; idx<4*144; idx+=256){
    int sl = idx/144;
    esl[idx] = (s0+sl < NSLICE)? E[(size_t)s0*144 + idx] : 0.f;
  }
  __syncthreads();
  for(int oi=t; oi<4*324; oi+=256){
    int sl = oi/324, rest = oi-324*sl;
    if (s0+sl >= NSLICE) continue;
    int y = rest/6, kz = rest-6*y;
    const float* base = &esl[sl*144];
    float fr=0.f, fi=0.f;
    #pragma unroll
    for(int kyi=0;kyi<12;kyi++){
      float er = base[(kyi*6+kz)*2], ei = base[(kyi*6+kz)*2+1];
      float tc = twc[kyi*54+y], ts = tws[kyi*54+y];
      fr += er*tc - ei*ts;
      fi += er*ts + ei*tc;
    }
    size_t ob = ((size_t)(s0+sl)*54 + y)*6 + kz;
    F[ob*2]=fr; F[ob*2+1]=fi;
  }
}

__global__ __launch_bounds__(256) void k_idft_z(const float* __restrict__ F,
    float* __restrict__ hs, double* __restrict__ st)
{
  __shared__ float rws[64*12];
  __shared__ float twc[5*54], tws[5*54];
  __shared__ float red[8];
  const int t = threadIdx.x;
  for(int idx=t; idx<5*54; idx+=256){
    int k = idx/54 + 1, z = idx%54;
    int m = (k*z)%54;
    float ang = (2.0f*PI_F/54.0f)*(float)m;
    twc[idx]=cosf(ang); tws[idx]=sinf(ang);
  }
  const int r0 = blockIdx.x*64;
  for(int idx=t; idx<768; idx+=256){
    int r = idx/12;
    rws[idx] = (r0+r < RT_ROWS)? F[(size_t)r0*12 + idx] : 0.f;
  }
  __syncthreads();
  const float inv = 1.0f/157464.0f;
  float lsum=0.f, lsq=0.f;
  for(int oi=t; oi<64*54; oi+=256){
    int r = oi/54, z = oi-54*r;
    if (r0+r < RT_ROWS){
      const float* fr = &rws[r*12];
      float acc = fr[0];
      #pragma unroll
      for(int k=1;k<=5;k++)
        acc += 2.0f*(fr[2*k]*twc[(k-1)*54+z] - fr[2*k+1]*tws[(k-1)*54+z]);
      acc *= inv;
      hs[(size_t)r0*54 + oi] = acc;
      lsum += acc; lsq += acc*acc;
    }
  }
  #pragma unroll
  for(int off=32; off; off>>=1){
    lsum += __shfl_down(lsum, off, 64);
    lsq  += __shfl_down(lsq,  off, 64);
  }
  if ((t&63)==0){ red[(t>>6)*2]=lsum; red[(t>>6)*2+1]=lsq; }
  __syncthreads();
  if (t==0){
    double s1 = (double)red[0]+red[2]+red[4]+red[6];
    double s2 = (double)red[1]+red[3]+red[5]+red[7];
    atomicAdd(st, s1); atomicAdd(st+1, s2);
  }
}

// ---------------- 1x1 conv (86->86), optional fused norm-add / gelu / out-stats ----------------
template<int ACT, int ADDN, int OSTAT>
__global__ __launch_bounds__(256,2) void k_conv86(
    const float* __restrict__ in, const float* __restrict__ W,
    const float* __restrict__ bias, const float* __restrict__ X,
    const float* __restrict__ g, const float* __restrict__ bg,
    const double* __restrict__ ist, double* __restrict__ ost,
    float* __restrict__ out)
{
  __shared__ alignas(16) float tin[CH*128];
  __shared__ alignas(16) float wt[32*96];
  __shared__ float red[8];
  const int t = threadIdx.x;
  const int s0 = blockIdx.x*128;
  for(int idx=t; idx<CH*128; idx+=256){
    int i = idx>>7, sp = idx&127;
    int s = s0+sp;
    tin[idx] = (s<SS3)? in[i*SS3 + s] : 0.f;
  }
  const int sg = t&31, rowq = t>>5;  // o = rowq*11 + j
  float acc[11][4];
  #pragma unroll
  for(int j=0;j<11;j++){acc[j][0]=0.f;acc[j][1]=0.f;acc[j][2]=0.f;acc[j][3]=0.f;}
  int c0 = 0;
  for(int chunk=0; chunk<3; chunk++){
    int cnt = (chunk<2)? 32 : 22;
    __syncthreads();
    for(int idx=t; idx<CH*cnt; idx+=256){
      int o = idx/cnt, ic = idx - o*cnt;
      wt[ic*96 + (o/11)*12 + (o%11)] = W[o*CH + c0 + ic];
    }
    __syncthreads();
    #pragma unroll 2
    for(int ii=0; ii<cnt; ii++){
      const float4 a = *reinterpret_cast<const float4*>(&tin[(c0+ii)*128 + sg*4]);
      const float4* wv = reinterpret_cast<const float4*>(&wt[ii*96 + rowq*12]);
      const float4 w0 = wv[0], w1 = wv[1], w2 = wv[2];
      const float wj[12] = {w0.x,w0.y,w0.z,w0.w,w1.x,w1.y,w1.z,w1.w,w2.x,w2.y,w2.z,w2.w};
      #pragma unroll
      for(int j=0;j<11;j++){
        acc[j][0] += wj[j]*a.x;
        acc[j][1] += wj[j]*a.y;
        acc[j][2] += wj[j]*a.z;
        acc[j][3] += wj[j]*a.w;
      }
    }
    c0 += cnt;
  }
  float mu=0.f, rs=1.f;
  if (ADDN){
    double m = ist[0]*GN_INV;
    double v = ist[1]*GN_INV - m*m;
    mu = (float)m;
    rs = (float)(1.0/sqrt(v + 1e-5));
  }
  float lsum=0.f, lsq=0.f;
  #pragma unroll
  for(int j=0;j<11;j++){
    int o = rowq*11 + j;
    if (o < CH){
      float bo = bias[o];
      float gg=1.f, bb=0.f;
      if (ADDN){ gg = g[o]; bb = bg[o]; }
      #pragma unroll
      for(int e=0;e<4;e++){
        int s = s0 + sg*4 + e;
        if (s < SS3){
          float v = acc[j][e] + bo;
          if (ADDN) v += (X[o*SS3 + s]-mu)*rs*gg + bb;
          if (ACT) v = gelu_f(v);
          if (OSTAT){ lsum += v; lsq += v*v; }
          out[o*SS3 + s] = v;
        }
      }
    }
  }
  if (OSTAT){
    #pragma unroll
    for(int off=32; off; off>>=1){
      lsum += __shfl_down(lsum, off, 64);
      lsq  += __shfl_down(lsq,  off, 64);
    }
    if ((t&63)==0){ red[(t>>6)*2]=lsum; red[(t>>6)*2+1]=lsq; }
    __syncthreads();
    if (t==0){
      double s1 = (double)red[0]+red[2]+red[4]+red[6];
      double s2 = (double)red[1]+red[3]+red[5]+red[7];
      atomicAdd(ost, s1); atomicAdd(ost+1, s2);
    }
  }
}

// ---------------- f_y: crop + transpose to [p][c] ----------------
__global__ __launch_bounds__(256) void k_build_fy(const float* __restrict__ h, float* __restrict__ fy)
{
  __shared__ float tile[CH*49];
  const int b = blockIdx.x;       // 0..2303
  const int x = b/48, y = b-48*x;
  const int t = threadIdx.x;
  for(int idx=t; idx<CH*48; idx+=256){
    int c = idx/48, z = idx-48*c;
    tile[c*49+z] = h[(size_t)c*SS3 + x*SS2 + y*54 + z];
  }
  __syncthreads();
  const size_t p0 = ((size_t)x*48 + y)*48;
  for(int idx=t; idx<48*CH; idx+=256){
    int z = idx/CH, c = idx-CH*z;
    fy[(p0+z)*CH + c] = tile[c*49+z];
  }
}

// ---------------- kin: [pair][96] bf16 = [y-embed(48) | q-embed(48)] ----------------
__global__ __launch_bounds__(256) void k_build_kin(const float* __restrict__ x_in,
    const int* __restrict__ nb_idx, unsigned short* __restrict__ kin, int pair0)
{
  int gidx = blockIdx.x*256 + threadIdx.x;
  int lp = gidx/96, col = gidx - lp*96;
  int pair = pair0 + lp;
  int qi = pair/24;
  int cc = col; bool isq = false;
  if (cc >= 48){ cc -= 48; isq = true; }
  int ci = cc>>4, e = cc&15;
  int f = e&7; bool is_sin = (e>=8);
  float coord;
  if (isq){
    coord = x_in[qi*3 + ci];
  } else {
    int pt = nb_idx[pair];
    int gcoord;
    if (ci==0) gcoord = pt/2304;
    else if (ci==1) gcoord = (pt/48)%48;
    else gcoord = pt%48;
    coord = gcoord*(1.0f/47.0f);
  }
  float freq = exp2f(-(float)f * 1.66096404744368117f);  // 10000^{-f/8}
  float ang = coord*freq;
  kin[gidx] = f2bf(is_sin ? sinf(ang) : cosf(ang));
}

// ---------------- MFMA GEMM: C[m][n] = act(sum_k A[m][k]*B[n][k] + bias[n]) ----------------
// A: bf16 [M][K], B: bf16 [N][K]  (both K-contiguous). 128x128 tile, BK=32,
// 4 waves x (4x4) 16x16x32 MFMA, global_load_lds width-16 staging (m97 structure).
template<int ACT, int OUT_BF16>
__global__ __launch_bounds__(256,2) void k_gemm_mfma(
    const unsigned short* __restrict__ A, const unsigned short* __restrict__ B,
    const float* __restrict__ bias, void* __restrict__ Cout,
    int M, int N, int K)
{
  __shared__ unsigned short As[128*32];
  __shared__ unsigned short Bs[128*32];
  const int t = threadIdx.x;
  const int lane = t & 63, w = t >> 6;
  const int wm = w >> 1, wn = w & 1;
  const int m0 = blockIdx.x*128, n0 = blockIdx.y*128;
  const int lr = lane >> 2, lq = lane & 3;     // staging: 16 rows x 4 quads per slot
  f32x4 acc[4][4];
  #pragma unroll
  for(int s=0;s<4;s++)
    #pragma unroll
    for(int n=0;n<4;n++) acc[s][n] = (f32x4){0.f,0.f,0.f,0.f};

  for(int k0=0;k0<K;k0+=32){
    __syncthreads();
    #pragma unroll
    for(int j=0;j<2;j++){
      int slot = w*2 + j;
      int row = slot*16 + lr;
      const unsigned short* ga = A + (size_t)(m0+row)*K + k0 + lq*8;
      __builtin_amdgcn_global_load_lds((const __attribute__((address_space(1))) void*)ga,
          (__attribute__((address_space(3))) void*)&As[slot*512], 16, 0, 0);
      int brow = n0 + row; if (brow > N-1) brow = N-1;
      const unsigned short* gb = B + (size_t)brow*K + k0 + lq*8;
      __builtin_amdgcn_global_load_lds((const __attribute__((address_space(1))) void*)gb,
          (__attribute__((address_space(3))) void*)&Bs[slot*512], 16, 0, 0);
    }
    __syncthreads();
    bf16x8 af[4], bg[4];
    #pragma unroll
    for(int s=0;s<4;s++)
      af[s] = *(const bf16x8*)&As[(wm*64 + s*16 + (lane&15))*32 + (lane>>4)*8];
    #pragma unroll
    for(int n=0;n<4;n++)
      bg[n] = *(const bf16x8*)&Bs[(wn*64 + n*16 + (lane&15))*32 + (lane>>4)*8];
    #pragma unroll
    for(int s=0;s<4;s++)
      #pragma unroll
      for(int n=0;n<4;n++)
        acc[s][n] = __builtin_amdgcn_mfma_f32_16x16x32_bf16(af[s], bg[n], acc[s][n], 0, 0, 0);
  }

  unsigned short* Cb = (unsigned short*)Cout;
  float* Cf = (float*)Cout;
  const int colb = n0 + wn*64 + (lane&15);
  const int rowb = m0 + wm*64 + (lane>>4)*4;
  #pragma unroll
  for(int n=0;n<4;n++){
    int col = colb + n*16;
    if (col < N){
      float bn = bias[col];
      #pragma unroll
      for(int s=0;s<4;s++){
        int row = rowb + s*16;
        #pragma unroll
        for(int r=0;r<4;r++){
          float v = acc[s][n][r] + bn;
          if (ACT) v = gelu_f(v);
          if (OUT_BF16) Cb[(size_t)(row+r)*N + col] = f2bf(v);
          else          Cf[(size_t)(row+r)*N + col] = v;
        }
      }
    }
  }
}

// ---------------- GNO reduce + projection head ----------------
__global__ __launch_bounds__(256) void k_gno_reduce(
    const float* __restrict__ K3, const float* __restrict__ fy,
    const int* __restrict__ nb_idx, const int* __restrict__ nb_mask,
    const float* __restrict__ p1w, const float* __restrict__ p1b,
    const float* __restrict__ p2w, const float* __restrict__ p2b,
    float* __restrict__ out)
{
  __shared__ float v[CH];
  __shared__ int   sidx[24];
  __shared__ float smk[24];
  __shared__ float red[4];
  const int i = blockIdx.x, t = threadIdx.x;
  if (t < 24){
    sidx[t] = nb_idx[i*24+t];
    smk[t]  = (nb_mask[i*24+t] != 0)? 1.f : 0.f;
  }
  __syncthreads();
  if (t < CH){
    float acc=0.f, den=0.f;
    for(int k=0;k<24;k++){
      float m = smk[k];
      den += m;
      if (m > 0.f)
        acc += K3[((size_t)(i*24+k))*CH + t]*fy[(size_t)sidx[k]*CH + t];
    }
    if (den < 1.f) den = 1.f;
    v[t] = acc/den;
  }
  __syncthreads();
  float a1 = p1b[t];
  for(int c=0;c<CH;c++) a1 += v[c]*p1w[t*CH + c];
  float part = gelu_f(a1)*p2w[t];
  #pragma unroll
  for(int off=32; off; off>>=1) part += __shfl_down(part, off, 64);
  if ((t&63)==0) red[t>>6] = part;
  __syncthreads();
  if (t==0) out[i] = red[0]+red[1]+red[2]+red[3] + p2b[0];
}

// ---------------- launch ----------------
extern "C" void kernel_launch(void* const* d_in, const int* in_sizes, int n_in,
                              void* d_out, int out_size, void* d_ws, size_t ws_size,
                              hipStream_t stream)
{
  (void)in_sizes; (void)n_in; (void)out_size; (void)ws_size;
  const float* x_in  = (const float*)d_in[0];
  const float* df    = (const float*)d_in[2];
  const int*   nbidx = (const int*)d_in[3];
  const int*   nbmsk = (const int*)d_in[4];
  const float* wlift = (const float*)d_in[5];
  const float* blift = (const float*)d_in[6];
  const float* spwr  = (const float*)d_in[7];
  const float* spwi  = (const float*)d_in[8];
  const float* wskip = (const float*)d_in[9];
  const float* bskip = (const float*)d_in[10];
  const float* m1w   = (const float*)d_in[11];
  const float* m1b   = (const float*)d_in[12];
  const float* m2w   = (const float*)d_in[13];
  const float* m2b   = (const float*)d_in[14];
  const float* wms   = (const float*)d_in[15];
  const float* bms   = (const float*)d_in[16];
  const float* g1w   = (const float*)d_in[17];
  const float* g1b   = (const float*)d_in[18];
  const float* g2w   = (const float*)d_in[19];
  const float* g2b   = (const float*)d_in[20];
  const float* k1w   = (const float*)d_in[21];
  const float* k1b   = (const float*)d_in[22];
  const float* k2w   = (const float*)d_in[23];
  const float* k2b   = (const float*)d_in[24];
  const float* k3w   = (const float*)d_in[25];
  const float* k3b   = (const float*)d_in[26];
  const float* p1w   = (const float*)d_in[27];
  const float* p1b   = (const float*)d_in[28];
  const float* p2w   = (const float*)d_in[29];
  const float* p2b   = (const float*)d_in[30];
  float* out = (float*)d_out;
  char* ws = (char*)d_ws;

  float* hA = (float*)(ws + OFF_HA);
  float* hB = (float*)(ws + OFF_HB);
  float* hS = (float*)(ws + OFF_HS);
  float* tB = (float*)(ws + OFF_T);
  float* fA = (float*)(ws + OFF_FA);
  float* fB = (float*)(ws + OFF_FB);
  float* fC = (float*)(ws + OFF_FC);
  float* fD = (float*)(ws + OFF_FD);
  float* fE = (float*)(ws + OFF_FE);
  double* st= (double*)(ws + OFF_ST);
  float* K3 = (float*)(ws + OFF_K3);
  float* fy = (float*)(ws + OFF_FY);
  unsigned short* kinb = (unsigned short*)(ws + OFF_KIN);
  unsigned short* Z1b  = (unsigned short*)(ws + OFF_Z1);
  unsigned short* Z2b  = (unsigned short*)(ws + OFF_Z2);
  unsigned short* w1b  = (unsigned short*)(ws + OFF_W1);
  unsigned short* w2b  = (unsigned short*)(ws + OFF_W2);
  unsigned short* w3b  = (unsigned short*)(ws + OFF_W3);

  k_zero_stats<<<1,64,0,stream>>>(st);
  k_lift<<<dim3(54,86),256,0,stream>>>(df, wlift, blift, hA);

  for(int l=0;l<4;l++){
    const float* wr_l = spwr + (size_t)l*4*CH*CH*216;
    const float* wi_l = spwi + (size_t)l*4*CH*CH*216;
    double* st1 = st + l*4;
    double* st2 = st + l*4 + 2;
    k_dft_z<<<3919,256,0,stream>>>(hA, fA);
    k_dft_y<<<1161,256,0,stream>>>(fA, fB);
    k_dft_x<<<86,256,0,stream>>>(fB, fC);
    k_mix<<<dim3(86,4),256,0,stream>>>(fC, wr_l, wi_l, fD);
    k_idft_x<<<86,256,0,stream>>>(fD, fE);
    k_idft_y<<<1161,256,0,stream>>>(fE, fA);
    k_idft_z<<<3919,256,0,stream>>>(fA, hS, st1);
    if (l<3) k_conv86<1,1,0><<<1231,256,0,stream>>>(hA, wskip+l*7396, bskip+l*86, hS, g1w+l*86, g1b+l*86, st1, nullptr, hB);
    else     k_conv86<0,1,0><<<1231,256,0,stream>>>(hA, wskip+l*7396, bskip+l*86, hS, g1w+l*86, g1b+l*86, st1, nullptr, hB);
    k_conv86<1,0,0><<<1231,256,0,stream>>>(hB, m1w+l*7396, m1b+l*86, nullptr, nullptr, nullptr, nullptr, nullptr, tB);
    k_conv86<0,0,1><<<1231,256,0,stream>>>(tB, m2w+l*7396, m2b+l*86, nullptr, nullptr, nullptr, nullptr, st2, hS);
    if (l<3) k_conv86<1,1,0><<<1231,256,0,stream>>>(hB, wms+l*7396, bms+l*86, hS, g2w+l*86, g2b+l*86, st2, nullptr, hA);
    else     k_conv86<0,1,0><<<1231,256,0,stream>>>(hB, wms+l*7396, bms+l*86, hS, g2w+l*86, g2b+l*86, st2, nullptr, hA);
  }

  k_build_fy<<<2304,256,0,stream>>>(hA, fy);

  // Convert GNO MLP weights to bf16 (overlays now-dead FNO buffers)
  k_f2bf<<<(512*96+255)/256,256,0,stream>>>(k1w, w1b, 512*96);
  k_f2bf<<<(256*512+255)/256,256,0,stream>>>(k2w, w2b, 256*512);
  k_f2bf<<<(86*256+255)/256,256,0,stream>>>(k3w, w3b, 86*256);

  for(int ch=0; ch<2; ch++){
    int pair0 = ch*CHUNK_M;
    k_build_kin<<<(CHUNK_M*96)/256,256,0,stream>>>(x_in, nbidx, kinb, pair0);
    k_gemm_mfma<1,1><<<dim3(CHUNK_M/128,4),256,0,stream>>>(kinb, w1b, k1b, (void*)Z1b, CHUNK_M, 512, 96);
    k_gemm_mfma<1,1><<<dim3(CHUNK_M/128,2),256,0,stream>>>(Z1b, w2b, k2b, (void*)Z2b, CHUNK_M, 256, 512);
    k_gemm_mfma<0,0><<<dim3(CHUNK_M/128,1),256,0,stream>>>(Z2b, w3b, k3b, (void*)(K3 + (size_t)pair0*CH), CHUNK_M, 86, 256);
  }

  k_gno_reduce<<<8192,256,0,stream>>>(K3, fy, nbidx, nbmsk, p1w, p1b, p2w, p2b, out);
}

// Round 3
// 2410.683 us; speedup vs baseline: 2.6838x; 1.4659x over previous
//
#include <hip/hip_runtime.h>
#include <math.h>

#define CH 86
#define SP 54
#define SS2 2916
#define SS3 157464
#define DG 48
#define MPAD 157568          /* 1231*128 */
#define RT_ROWS (CH*SS2)     /* 250776 rows of (i,x,y) */
#define NSLICE (CH*SP)       /* 4644 */
#define PI_F 3.14159265358979323846f
#define GN_INV (1.0/13541904.0)

static constexpr size_t A512(size_t x){ return (x + 511) & ~((size_t)511); }
static constexpr size_t HBYTES = (size_t)CH*SS3*4;            // 54,167,616
static constexpr size_t ABYTES = (size_t)MPAD*96*2;           // 30,253,056 (bf16 act)
static constexpr size_t XBYTES = (size_t)MPAD*96*4;           // 60,506,112 (fp32 [s][96])
static constexpr size_t FAB = (size_t)CH*SS2*6*8;             // 12,037,248
static constexpr size_t FBB = (size_t)CH*SP*12*6*8;           // 2,674,944
static constexpr size_t FCB = (size_t)CH*864*8;               // 594,432
static constexpr size_t OFF_HA = 0;
static constexpr size_t OFF_HS = OFF_HA + A512(HBYTES);
static constexpr size_t OFF_AB = OFF_HS + A512(HBYTES);
static constexpr size_t OFF_BB = OFF_AB + A512(ABYTES);
static constexpr size_t OFF_TB = OFF_BB + A512(ABYTES);
static constexpr size_t OFF_XSC= OFF_TB + A512(ABYTES);       // hm fp32 [s][96]; becomes FY at l=3
static constexpr size_t OFF_FA = OFF_XSC+ A512(XBYTES);
static constexpr size_t OFF_FB = OFF_FA + A512(FAB);
static constexpr size_t OFF_FC = OFF_FB + A512(FBB);
static constexpr size_t OFF_FD = OFF_FC + A512(FCB);
static constexpr size_t OFF_FE = OFF_FD + A512(FCB);
static constexpr size_t OFF_ST = OFF_FE + A512(FBB);
static constexpr size_t OFF_WB = OFF_ST + 512;                // 16 conv weights bf16 [96][96]
static constexpr size_t OFF_K3 = OFF_WB + A512((size_t)16*96*96*2);
// GNO chunk buffers overlay [0 .. OFF_XSC) (hA/hS/Ab/Bb/Tb dead after FNO). 2 chunks.
static constexpr int    CHUNK_M = 98304;
static constexpr size_t OFF_KIN = 0;                                    // bf16 CHUNK*96
static constexpr size_t OFF_Z1  = A512((size_t)CHUNK_M*96*2);           // bf16 CHUNK*512
static constexpr size_t OFF_Z2  = OFF_Z1 + A512((size_t)CHUNK_M*512*2); // bf16 CHUNK*256
static constexpr size_t OFF_W1  = OFF_Z2 + A512((size_t)CHUNK_M*256*2);
static constexpr size_t OFF_W2  = OFF_W1 + A512((size_t)512*96*2);
static constexpr size_t OFF_W3  = OFF_W2 + A512((size_t)256*512*2);

typedef __attribute__((ext_vector_type(8))) short bf16x8;
typedef __attribute__((ext_vector_type(4))) float f32x4;

__device__ __forceinline__ float gelu_f(float x){
  return 0.5f*x*(1.0f + erff(x*0.70710678118654752440f));
}
__device__ __forceinline__ unsigned short f2bf(float x){
  unsigned u = __float_as_uint(x);
  u += 0x7fffu + ((u>>16)&1u);
  return (unsigned short)(u>>16);
}

__global__ void k_zero_stats(double* st){ if (threadIdx.x < 16) st[threadIdx.x] = 0.0; }

__global__ __launch_bounds__(256) void k_f2bf(const float* __restrict__ in,
    unsigned short* __restrict__ out, int n)
{
  int i = blockIdx.x*256 + threadIdx.x;
  if (i < n) out[i] = f2bf(in[i]);
}

// conv weight prep: [86][86] fp32 -> [96][96] bf16 zero-padded
__global__ __launch_bounds__(256) void k_wprep(const float* __restrict__ src,
    unsigned short* __restrict__ dst, int slot)
{
  int l = blockIdx.y;
  int idx = blockIdx.x*256 + threadIdx.x;   // 0..9215
  int n = idx/96, k = idx-96*n;
  unsigned short v = 0;
  if (n < 86 && k < 86) v = f2bf(src[(size_t)l*7396 + n*86 + k]);
  dst[(size_t)(l*4+slot)*9216 + idx] = v;
}

// ---------------- lift: writes hA fp32 [c][s] + Ab bf16 [s][96] ----------------
__global__ __launch_bounds__(256) void k_lift(const float* __restrict__ df,
    const float* __restrict__ wl, const float* __restrict__ bl,
    float* __restrict__ hA, unsigned short* __restrict__ Ab)
{
  __shared__ float vals[128*96];
  const int t = threadIdx.x;
  const int s0 = blockIdx.x*128;
  for(int idx=t; idx<128*96; idx+=256){
    int sl = idx/96, o = idx-96*sl;
    int s = s0+sl;
    float v = 0.f;
    if (o < 86){
      int x = s/2916, r2 = s-2916*x, y = r2/54, z = r2-54*y;
      if (x<DG && y<DG && z<DG){
        int p = (x*DG + y)*DG + z;
        v = wl[o*5]*df[p] + wl[o*5+1]*df[110592+p]
          + wl[o*5+2]*(x*(1.0f/47.0f)) + wl[o*5+3]*(y*(1.0f/47.0f))
          + wl[o*5+4]*(z*(1.0f/47.0f)) + bl[o];
      }
    }
    vals[idx] = v;
  }
  __syncthreads();
  for(int idx=t; idx<128*96; idx+=256)
    Ab[(size_t)s0*96 + idx] = f2bf(vals[idx]);
  for(int idx=t; idx<86*128; idx+=256){
    int c = idx/128, sl = idx-128*c;
    int s = s0+sl;
    if (s < SS3) hA[(size_t)c*SS3 + s] = vals[sl*96 + c];
  }
}

// ---------------- forward partial DFT ----------------
__global__ __launch_bounds__(256) void k_dft_z(const float* __restrict__ h, float* __restrict__ A)
{
  __shared__ alignas(16) float rows[64*55];
  __shared__ float twc[6*54], tws[6*54];
  const int t = threadIdx.x;
  for(int idx=t; idx<6*54; idx+=256){
    int k = idx/54, z = idx-54*k;
    int m = (k*z)%54;
    float ang = -(2.0f*PI_F/54.0f)*(float)m;
    twc[idx]=cosf(ang); tws[idx]=sinf(ang);
  }
  const int r0 = blockIdx.x*64;
  for(int idx=t; idx<64*54; idx+=256){
    int r = idx/54;
    rows[r*55 + (idx-54*r)] = (r0+r < RT_ROWS)? h[(size_t)r0*54 + idx] : 0.f;
  }
  __syncthreads();
  for(int oi=t; oi<768; oi+=256){
    int r = oi & 63;
    int k = (oi>>6)%6;
    int part = oi/384;
    if (r0+r < RT_ROWS){
      const float* tw = part? tws : twc;
      const float* rp = &rows[r*55];
      const float* twk = &tw[k*54];
      float acc=0.f;
      #pragma unroll 6
      for(int z=0;z<54;z++) acc += rp[z]*twk[z];
      A[((size_t)(r0+r)*6 + k)*2 + part] = acc;
    }
  }
}

__global__ __launch_bounds__(256) void k_dft_y(const float* __restrict__ A, float* __restrict__ B)
{
  __shared__ float asl[4*648];
  __shared__ float twc[12*54], tws[12*54];
  const int t = threadIdx.x;
  for(int idx=t; idx<12*54; idx+=256){
    int kyi = idx/54, y = idx-54*kyi;
    int ky = (kyi<6)? kyi : (42+kyi);
    int m = (ky*y)%54;
    float ang = -(2.0f*PI_F/54.0f)*(float)m;
    twc[idx]=cosf(ang); tws[idx]=sinf(ang);
  }
  const int s0 = blockIdx.x*4;
  for(int idx=t; idx<4*648; idx+=256){
    int sl = idx/648;
    asl[idx] = (s0+sl < NSLICE)? A[(size_t)s0*648 + idx] : 0.f;
  }
  __syncthreads();
  for(int oi=t; oi<4*72; oi+=256){
    int sl = oi/72, o = oi-72*sl;
    if (s0+sl >= NSLICE) continue;
    int kyi = o/6, kz = o-6*kyi;
    const float* base = &asl[sl*648];
    float cr=0.f, ci=0.f;
    for(int y=0;y<54;y++){
      float ar = base[(y*6+kz)*2], ai = base[(y*6+kz)*2+1];
      float tc = twc[kyi*54+y], ts = tws[kyi*54+y];
      cr += ar*tc - ai*ts;
      ci += ar*ts + ai*tc;
    }
    size_t ob = ((size_t)(s0+sl)*12 + kyi)*6 + kz;
    B[ob*2]=cr; B[ob*2+1]=ci;
  }
}

__global__ __launch_bounds__(256) void k_dft_x(const float* __restrict__ B, float* __restrict__ C)
{
  __shared__ float bsl[7776];
  __shared__ float twc[12*54], tws[12*54];
  const int t = threadIdx.x;
  const int i = blockIdx.x;
  for(int idx=t; idx<12*54; idx+=256){
    int kxi = idx/54, x = idx-54*kxi;
    int kx = (kxi<6)? kxi : (42+kxi);
    int m = (kx*x)%54;
    float ang = -(2.0f*PI_F/54.0f)*(float)m;
    twc[idx]=cosf(ang); tws[idx]=sinf(ang);
  }
  for(int idx=t; idx<7776; idx+=256) bsl[idx] = B[(size_t)i*7776 + idx];
  __syncthreads();
  for(int oi=t; oi<864; oi+=256){
    int kxi = oi/72, rest = oi-72*kxi;
    float cr=0.f, ci=0.f;
    for(int x=0;x<54;x++){
      float br = bsl[(x*72+rest)*2], bi = bsl[(x*72+rest)*2+1];
      float tc = twc[kxi*54+x], ts = tws[kxi*54+x];
      cr += br*tc - bi*ts;
      ci += br*ts + bi*tc;
    }
    int kyi = rest/6, kz = rest-6*kyi;
    int c = ((kxi>=6)?2:0) + ((kyi>=6)?1:0);
    int f = ((kxi%6)*6 + (kyi%6))*6 + kz;
    size_t ob = ((size_t)i*4 + c)*216 + f;
    C[ob*2]=cr; C[ob*2+1]=ci;
  }
}

__global__ __launch_bounds__(256) void k_mix(const float* __restrict__ C,
    const float* __restrict__ wr, const float* __restrict__ wi, float* __restrict__ D)
{
  const int f = threadIdx.x;
  if (f >= 216) return;
  const int o = blockIdx.x, c = blockIdx.y;
  const size_t wstride = (size_t)CH*216;
  const float* wrp = wr + ((size_t)c*CH*CH + o)*216 + f;
  const float* wip = wi + ((size_t)c*CH*CH + o)*216 + f;
  const float* cp  = C + ((size_t)c*216 + f)*2;
  float ar=0.f, ai=0.f;
  #pragma unroll 4
  for(int i=0;i<CH;i++){
    float cr = cp[0], cim = cp[1];
    float xr = *wrp, xi = *wip;
    ar += cr*xr - cim*xi;
    ai += cr*xi + cim*xr;
    wrp += wstride; wip += wstride;
    cp += 864*2;
  }
  int mx = f/36, my = (f/6)%6, kz = f%6;
  int kxi = mx + ((c>=2)?6:0);
  int kyi = my + ((c&1)?6:0);
  size_t ob = (((size_t)o*12 + kxi)*12 + kyi)*6 + kz;
  D[ob*2]=ar; D[ob*2+1]=ai;
}

// ---------------- inverse partial DFT ----------------
__global__ __launch_bounds__(256) void k_idft_x(const float* __restrict__ D, float* __restrict__ E)
{
  __shared__ float dsl[1728];
  __shared__ float twc[12*54], tws[12*54];
  const int t = threadIdx.x;
  const int o = blockIdx.x;
  for(int idx=t; idx<12*54; idx+=256){
    int kxi = idx/54, x = idx-54*kxi;
    int kx = (kxi<6)? kxi : (42+kxi);
    int m = (kx*x)%54;
    float ang = (2.0f*PI_F/54.0f)*(float)m;
    twc[idx]=cosf(ang); tws[idx]=sinf(ang);
  }
  for(int idx=t; idx<1728; idx+=256) dsl[idx] = D[(size_t)o*1728 + idx];
  __syncthreads();
  for(int oi=t; oi<3888; oi+=256){
    int x = oi/72, rest = oi-72*x;
    float er=0.f, ei=0.f;
    #pragma unroll
    for(int kxi=0;kxi<12;kxi++){
      float dr = dsl[(kxi*72+rest)*2], di = dsl[(kxi*72+rest)*2+1];
      float tc = twc[kxi*54+x], ts = tws[kxi*54+x];
      er += dr*tc - di*ts;
      ei += dr*ts + di*tc;
    }
    size_t ob = (size_t)o*3888 + oi;
    E[ob*2]=er; E[ob*2+1]=ei;
  }
}

__global__ __launch_bounds__(256) void k_idft_y(const float* __restrict__ E, float* __restrict__ F)
{
  __shared__ float esl[4*144];
  __shared__ float twc[12*54], tws[12*54];
  const int t = threadIdx.x;
  for(int idx=t; idx<12*54; idx+=256){
    int kyi = idx/54, y = idx-54*kyi;
    int ky = (kyi<6)? kyi : (42+kyi);
    int m = (ky*y)%54;
    float ang = (2.0f*PI_F/54.0f)*(float)m;
    twc[idx]=cosf(ang); tws[idx]=sinf(ang);
  }
  const int s0 = blockIdx.x*4;
  for(int idx=t; idx<4*144; idx+=256){
    int sl = idx/144;
    esl[idx] = (s0+sl < NSLICE)? E[(size_t)s0*144 + idx] : 0.f;
  }
  __syncthreads();
  for(int oi=t; oi<4*324; oi+=256){
    int sl = oi/324, rest = oi-324*sl;
    if (s0+sl >= NSLICE) continue;
    int y = rest/6, kz = rest-6*y;
    const float* base = &esl[sl*144];
    float fr=0.f, fi=0.f;
    #pragma unroll
    for(int kyi=0;kyi<12;kyi++){
      float er = base[(kyi*6+kz)*2], ei = base[(kyi*6+kz)*2+1];
      float tc = twc[kyi*54+y], ts = tws[kyi*54+y];
      fr += er*tc - ei*ts;
      fi += er*ts + ei*tc;
    }
    size_t ob = ((size_t)(s0+sl)*54 + y)*6 + kz;
    F[ob*2]=fr; F[ob*2+1]=fi;
  }
}

__global__ __launch_bounds__(256) void k_idft_z(const float* __restrict__ F,
    float* __restrict__ hs, double* __restrict__ st)
{
  __shared__ float rws[64*12];
  __shared__ float twc[5*54], tws[5*54];
  __shared__ float red[8];
  const int t = threadIdx.x;
  for(int idx=t; idx<5*54; idx+=256){
    int k = idx/54 + 1, z = idx%54;
    int m = (k*z)%54;
    float ang = (2.0f*PI_F/54.0f)*(float)m;
    twc[idx]=cosf(ang); tws[idx]=sinf(ang);
  }
  const int r0 = blockIdx.x*64;
  for(int idx=t; idx<768; idx+=256){
    int r = idx/12;
    rws[idx] = (r0+r < RT_ROWS)? F[(size_t)r0*12 + idx] : 0.f;
  }
  __syncthreads();
  const float inv = 1.0f/157464.0f;
  float lsum=0.f, lsq=0.f;
  for(int oi=t; oi<64*54; oi+=256){
    int r = oi/54, z = oi-54*r;
    if (r0+r < RT_ROWS){
      const float* fr = &rws[r*12];
      float acc = fr[0];
      #pragma unroll
      for(int k=1;k<=5;k++)
        acc += 2.0f*(fr[2*k]*twc[(k-1)*54+z] - fr[2*k+1]*tws[(k-1)*54+z]);
      acc *= inv;
      hs[(size_t)r0*54 + oi] = acc;
      lsum += acc; lsq += acc*acc;
    }
  }
  #pragma unroll
  for(int off=32; off; off>>=1){
    lsum += __shfl_down(lsum, off, 64);
    lsq  += __shfl_down(lsq,  off, 64);
  }
  if ((t&63)==0){ red[(t>>6)*2]=lsum; red[(t>>6)*2+1]=lsq; }
  __syncthreads();
  if (t==0){
    double s1 = (double)red[0]+red[2]+red[4]+red[6];
    double s2 = (double)red[1]+red[3]+red[5]+red[7];
    atomicAdd(st, s1); atomicAdd(st+1, s2);
  }
}

// ---------------- MFMA 1x1 conv: C[s][o] = act(norm-add)(sum_k A[s][k] W[o][k] + b[o]) ----
// A bf16 [MPAD][96], W bf16 [96][96] (rows>=86 zero). 128x96 tile, BK=32, 4 waves
// stacked in M (each 32 rows x 96 cols => 2x6 16x16x32 MFMA).
// ADDN: 0 none, 1 X fp32 [c][SS3], 2 X fp32 [MPAD][96]. Outputs optional.
template<int ACT, int ADDN, int OSTAT, int OB, int OCS, int OSC>
__global__ __launch_bounds__(256) void k_convm(
    const unsigned short* __restrict__ Ain, const unsigned short* __restrict__ Wb,
    const float* __restrict__ bias,
    const float* __restrict__ Xcs, const float* __restrict__ Xsc,
    const float* __restrict__ g, const float* __restrict__ bg,
    const double* __restrict__ ist, double* __restrict__ ost,
    unsigned short* __restrict__ outb, float* __restrict__ outcs, float* __restrict__ outsc)
{
  __shared__ unsigned short As[128*32];
  __shared__ unsigned short Bs[96*32];
  __shared__ float red[8];
  const int t = threadIdx.x, lane = t&63, w = t>>6;
  const int m0 = blockIdx.x*128;
  const int lr = lane>>2, lq = lane&3;
  f32x4 acc[2][6];
  #pragma unroll
  for(int s=0;s<2;s++)
    #pragma unroll
    for(int n=0;n<6;n++) acc[s][n] = (f32x4){0.f,0.f,0.f,0.f};

  #pragma unroll
  for(int k0=0;k0<96;k0+=32){
    __syncthreads();
    #pragma unroll
    for(int j=0;j<4;j++){
      int slot = j*4 + w;
      if (slot < 8){
        int row = slot*16 + lr;
        const unsigned short* ga = Ain + (size_t)(m0+row)*96 + k0 + lq*8;
        __builtin_amdgcn_global_load_lds((const __attribute__((address_space(1))) void*)ga,
            (__attribute__((address_space(3))) void*)&As[slot*512], 16, 0, 0);
      } else if (slot < 14){
        int bs = slot-8;
        int row = bs*16 + lr;
        const unsigned short* gb = Wb + (size_t)row*96 + k0 + lq*8;
        __builtin_amdgcn_global_load_lds((const __attribute__((address_space(1))) void*)gb,
            (__attribute__((address_space(3))) void*)&Bs[bs*512], 16, 0, 0);
      }
    }
    __syncthreads();
    bf16x8 af[2], bf[6];
    #pragma unroll
    for(int s=0;s<2;s++)
      af[s] = *(const bf16x8*)&As[(w*32 + s*16 + (lane&15))*32 + (lane>>4)*8];
    #pragma unroll
    for(int n=0;n<6;n++)
      bf[n] = *(const bf16x8*)&Bs[(n*16 + (lane&15))*32 + (lane>>4)*8];
    #pragma unroll
    for(int s=0;s<2;s++)
      #pragma unroll
      for(int n=0;n<6;n++)
        acc[s][n] = __builtin_amdgcn_mfma_f32_16x16x32_bf16(af[s], bf[n], acc[s][n], 0, 0, 0);
  }

  float mu=0.f, rs=1.f;
  if (ADDN){
    double m = ist[0]*GN_INV;
    double v = ist[1]*GN_INV - m*m;
    mu = (float)m;
    rs = (float)(1.0/sqrt(v + 1e-5));
  }
  float lsum=0.f, lsq=0.f;
  const int colb = lane&15, rowq = (lane>>4)*4;
  #pragma unroll
  for(int n=0;n<6;n++){
    int col = n*16 + colb;
    bool cv = (col < CH);
    float bn=0.f, gg=1.f, bb=0.f;
    if (cv){
      bn = bias[col];
      if (ADDN){ gg = g[col]; bb = bg[col]; }
    }
    #pragma unroll
    for(int s=0;s<2;s++){
      #pragma unroll
      for(int r=0;r<4;r++){
        int row = m0 + w*32 + s*16 + rowq + r;
        float v = 0.f;
        if (cv){
          v = acc[s][n][r] + bn;
          if (ADDN==1){ if (row < SS3) v += (Xcs[(size_t)col*SS3 + row]-mu)*rs*gg + bb; }
          if (ADDN==2){ v += (Xsc[(size_t)row*96 + col]-mu)*rs*gg + bb; }
          if (ACT) v = gelu_f(v);
          if (OSTAT){ if (row < SS3){ lsum += v; lsq += v*v; } }
        }
        if (OB) outb[(size_t)row*96 + col] = f2bf(v);
        if (OCS){ if (cv && row < SS3) outcs[(size_t)col*SS3 + row] = v; }
        if (OSC) outsc[(size_t)row*96 + col] = v;
      }
    }
  }
  if (OSTAT){
    #pragma unroll
    for(int off=32; off; off>>=1){
      lsum += __shfl_down(lsum, off, 64);
      lsq  += __shfl_down(lsq,  off, 64);
    }
    if ((lane)==0){ red[w*2]=lsum; red[w*2+1]=lsq; }
    __syncthreads();
    if (t==0){
      double s1 = (double)red[0]+red[2]+red[4]+red[6];
      double s2 = (double)red[1]+red[3]+red[5]+red[7];
      atomicAdd(ost, s1); atomicAdd(ost+1, s2);
    }
  }
}

// ---------------- kin: [pair][96] bf16 = [y-embed(48) | q-embed(48)] ----------------
__global__ __launch_bounds__(256) void k_build_kin(const float* __restrict__ x_in,
    const int* __restrict__ nb_idx, unsigned short* __restrict__ kin, int pair0)
{
  int gidx = blockIdx.x*256 + threadIdx.x;
  int lp = gidx/96, col = gidx - lp*96;
  int pair = pair0 + lp;
  int qi = pair/24;
  int cc = col; bool isq = false;
  if (cc >= 48){ cc -= 48; isq = true; }
  int ci = cc>>4, e = cc&15;
  int f = e&7; bool is_sin = (e>=8);
  float coord;
  if (isq){
    coord = x_in[qi*3 + ci];
  } else {
    int pt = nb_idx[pair];
    int gcoord;
    if (ci==0) gcoord = pt/2304;
    else if (ci==1) gcoord = (pt/48)%48;
    else gcoord = pt%48;
    coord = gcoord*(1.0f/47.0f);
  }
  float freq = exp2f(-(float)f * 1.66096404744368117f);  // 10000^{-f/8}
  float ang = coord*freq;
  kin[gidx] = f2bf(is_sin ? sinf(ang) : cosf(ang));
}

// ---------------- MFMA GEMM: C[m][n] = act(sum_k A[m][k]*B[n][k] + bias[n]) ----------------
template<int ACT, int OUT_BF16>
__global__ __launch_bounds__(256,2) void k_gemm_mfma(
    const unsigned short* __restrict__ A, const unsigned short* __restrict__ B,
    const float* __restrict__ bias, void* __restrict__ Cout,
    int M, int N, int K)
{
  __shared__ unsigned short As[128*32];
  __shared__ unsigned short Bs[128*32];
  const int t = threadIdx.x;
  const int lane = t & 63, w = t >> 6;
  const int wm = w >> 1, wn = w & 1;
  const int m0 = blockIdx.x*128, n0 = blockIdx.y*128;
  const int lr = lane >> 2, lq = lane & 3;
  f32x4 acc[4][4];
  #pragma unroll
  for(int s=0;s<4;s++)
    #pragma unroll
    for(int n=0;n<4;n++) acc[s][n] = (f32x4){0.f,0.f,0.f,0.f};

  for(int k0=0;k0<K;k0+=32){
    __syncthreads();
    #pragma unroll
    for(int j=0;j<2;j++){
      int slot = w*2 + j;
      int row = slot*16 + lr;
      const unsigned short* ga = A + (size_t)(m0+row)*K + k0 + lq*8;
      __builtin_amdgcn_global_load_lds((const __attribute__((address_space(1))) void*)ga,
          (__attribute__((address_space(3))) void*)&As[slot*512], 16, 0, 0);
      int brow = n0 + row; if (brow > N-1) brow = N-1;
      const unsigned short* gb = B + (size_t)brow*K + k0 + lq*8;
      __builtin_amdgcn_global_load_lds((const __attribute__((address_space(1))) void*)gb,
          (__attribute__((address_space(3))) void*)&Bs[slot*512], 16, 0, 0);
    }
    __syncthreads();
    bf16x8 af[4], bg[4];
    #pragma unroll
    for(int s=0;s<4;s++)
      af[s] = *(const bf16x8*)&As[(wm*64 + s*16 + (lane&15))*32 + (lane>>4)*8];
    #pragma unroll
    for(int n=0;n<4;n++)
      bg[n] = *(const bf16x8*)&Bs[(wn*64 + n*16 + (lane&15))*32 + (lane>>4)*8];
    #pragma unroll
    for(int s=0;s<4;s++)
      #pragma unroll
      for(int n=0;n<4;n++)
        acc[s][n] = __builtin_amdgcn_mfma_f32_16x16x32_bf16(af[s], bg[n], acc[s][n], 0, 0, 0);
  }

  unsigned short* Cb = (unsigned short*)Cout;
  float* Cf = (float*)Cout;
  const int colb = n0 + wn*64 + (lane&15);
  const int rowb = m0 + wm*64 + (lane>>4)*4;
  #pragma unroll
  for(int n=0;n<4;n++){
    int col = colb + n*16;
    if (col < N){
      float bn = bias[col];
      #pragma unroll
      for(int s=0;s<4;s++){
        int row = rowb + s*16;
        #pragma unroll
        for(int r=0;r<4;r++){
          float v = acc[s][n][r] + bn;
          if (ACT) v = gelu_f(v);
          if (OUT_BF16) Cb[(size_t)(row+r)*N + col] = f2bf(v);
          else          Cf[(size_t)(row+r)*N + col] = v;
        }
      }
    }
  }
}

// ---------------- GNO reduce + projection head ----------------
__global__ __launch_bounds__(256) void k_gno_reduce(
    const float* __restrict__ K3, const float* __restrict__ FY,
    const int* __restrict__ nb_idx, const int* __restrict__ nb_mask,
    const float* __restrict__ p1w, const float* __restrict__ p1b,
    const float* __restrict__ p2w, const float* __restrict__ p2b,
    float* __restrict__ out)
{
  __shared__ float v[CH];
  __shared__ int   sidx[24];
  __shared__ float smk[24];
  __shared__ float red[4];
  const int i = blockIdx.x, t = threadIdx.x;
  if (t < 24){
    int pt = nb_idx[i*24+t];
    int x = pt/2304, rem = pt-2304*x, y = rem/48, z = rem-48*y;
    sidx[t] = x*2916 + y*54 + z;      // spatial index in 54^3 layout
    smk[t]  = (nb_mask[i*24+t] != 0)? 1.f : 0.f;
  }
  __syncthreads();
  if (t < CH){
    float acc=0.f, den=0.f;
    for(int k=0;k<24;k++){
      float m = smk[k];
      den += m;
      if (m > 0.f)
        acc += K3[((size_t)(i*24+k))*CH + t]*FY[(size_t)sidx[k]*96 + t];
    }
    if (den < 1.f) den = 1.f;
    v[t] = acc/den;
  }
  __syncthreads();
  float a1 = p1b[t];
  for(int c=0;c<CH;c++) a1 += v[c]*p1w[t*CH + c];
  float part = gelu_f(a1)*p2w[t];
  #pragma unroll
  for(int off=32; off; off>>=1) part += __shfl_down(part, off, 64);
  if ((t&63)==0) red[t>>6] = part;
  __syncthreads();
  if (t==0) out[i] = red[0]+red[1]+red[2]+red[3] + p2b[0];
}

// ---------------- launch ----------------
extern "C" void kernel_launch(void* const* d_in, const int* in_sizes, int n_in,
                              void* d_out, int out_size, void* d_ws, size_t ws_size,
                              hipStream_t stream)
{
  (void)in_sizes; (void)n_in; (void)out_size; (void)ws_size;
  const float* x_in  = (const float*)d_in[0];
  const float* df    = (const float*)d_in[2];
  const int*   nbidx = (const int*)d_in[3];
  const int*   nbmsk = (const int*)d_in[4];
  const float* wlift = (const float*)d_in[5];
  const float* blift = (const float*)d_in[6];
  const float* spwr  = (const float*)d_in[7];
  const float* spwi  = (const float*)d_in[8];
  const float* wskip = (const float*)d_in[9];
  const float* bskip = (const float*)d_in[10];
  const float* m1w   = (const float*)d_in[11];
  const float* m1b   = (const float*)d_in[12];
  const float* m2w   = (const float*)d_in[13];
  const float* m2b   = (const float*)d_in[14];
  const float* wms   = (const float*)d_in[15];
  const float* bms   = (const float*)d_in[16];
  const float* g1w   = (const float*)d_in[17];
  const float* g1b   = (const float*)d_in[18];
  const float* g2w   = (const float*)d_in[19];
  const float* g2b   = (const float*)d_in[20];
  const float* k1w   = (const float*)d_in[21];
  const float* k1b   = (const float*)d_in[22];
  const float* k2w   = (const float*)d_in[23];
  const float* k2b   = (const float*)d_in[24];
  const float* k3w   = (const float*)d_in[25];
  const float* k3b   = (const float*)d_in[26];
  const float* p1w   = (const float*)d_in[27];
  const float* p1b   = (const float*)d_in[28];
  const float* p2w   = (const float*)d_in[29];
  const float* p2b   = (const float*)d_in[30];
  float* out = (float*)d_out;
  char* ws = (char*)d_ws;

  float* hA = (float*)(ws + OFF_HA);
  float* hS = (float*)(ws + OFF_HS);
  unsigned short* Ab = (unsigned short*)(ws + OFF_AB);
  unsigned short* Bb = (unsigned short*)(ws + OFF_BB);
  unsigned short* Tb = (unsigned short*)(ws + OFF_TB);
  float* Xsc = (float*)(ws + OFF_XSC);
  float* fA = (float*)(ws + OFF_FA);
  float* fB = (float*)(ws + OFF_FB);
  float* fC = (float*)(ws + OFF_FC);
  float* fD = (float*)(ws + OFF_FD);
  float* fE = (float*)(ws + OFF_FE);
  double* st= (double*)(ws + OFF_ST);
  unsigned short* Wb = (unsigned short*)(ws + OFF_WB);
  float* K3 = (float*)(ws + OFF_K3);
  unsigned short* kinb = (unsigned short*)(ws + OFF_KIN);
  unsigned short* Z1b  = (unsigned short*)(ws + OFF_Z1);
  unsigned short* Z2b  = (unsigned short*)(ws + OFF_Z2);
  unsigned short* w1b  = (unsigned short*)(ws + OFF_W1);
  unsigned short* w2b  = (unsigned short*)(ws + OFF_W2);
  unsigned short* w3b  = (unsigned short*)(ws + OFF_W3);

  k_zero_stats<<<1,64,0,stream>>>(st);
  k_wprep<<<dim3(36,4),256,0,stream>>>(wskip, Wb, 0);
  k_wprep<<<dim3(36,4),256,0,stream>>>(m1w,   Wb, 1);
  k_wprep<<<dim3(36,4),256,0,stream>>>(m2w,   Wb, 2);
  k_wprep<<<dim3(36,4),256,0,stream>>>(wms,   Wb, 3);
  k_lift<<<1231,256,0,stream>>>(df, wlift, blift, hA, Ab);

  for(int l=0;l<4;l++){
    const float* wr_l = spwr + (size_t)l*4*CH*CH*216;
    const float* wi_l = spwi + (size_t)l*4*CH*CH*216;
    double* st1 = st + l*4;
    double* st2 = st + l*4 + 2;
    k_dft_z<<<3919,256,0,stream>>>(hA, fA);
    k_dft_y<<<1161,256,0,stream>>>(fA, fB);
    k_dft_x<<<86,256,0,stream>>>(fB, fC);
    k_mix<<<dim3(86,4),256,0,stream>>>(fC, wr_l, wi_l, fD);
    k_idft_x<<<86,256,0,stream>>>(fD, fE);
    k_idft_y<<<1161,256,0,stream>>>(fE, fA);
    k_idft_z<<<3919,256,0,stream>>>(fA, hS, st1);
    const unsigned short* Wskip = Wb + (size_t)(l*4+0)*9216;
    const unsigned short* Wm1   = Wb + (size_t)(l*4+1)*9216;
    const unsigned short* Wm2   = Wb + (size_t)(l*4+2)*9216;
    const unsigned short* Wms   = Wb + (size_t)(l*4+3)*9216;
    // hB = act(gn1(hS) + conv(hA,wskip))
    if (l<3) k_convm<1,1,0,1,0,0><<<1231,256,0,stream>>>(Ab, Wskip, bskip+l*86, hS, nullptr, g1w+l*86, g1b+l*86, st1, nullptr, Bb, nullptr, nullptr);
    else     k_convm<0,1,0,1,0,0><<<1231,256,0,stream>>>(Ab, Wskip, bskip+l*86, hS, nullptr, g1w+l*86, g1b+l*86, st1, nullptr, Bb, nullptr, nullptr);
    // tB = gelu(conv(hB,m1))
    k_convm<1,0,0,1,0,0><<<1231,256,0,stream>>>(Bb, Wm1, m1b+l*86, nullptr, nullptr, nullptr, nullptr, nullptr, nullptr, Tb, nullptr, nullptr);
    // hm = conv(tB,m2) -> Xsc fp32 [s][96], + stats2
    k_convm<0,0,1,0,0,1><<<1231,256,0,stream>>>(Tb, Wm2, m2b+l*86, nullptr, nullptr, nullptr, nullptr, nullptr, st2, nullptr, nullptr, Xsc);
    // h = act(gn2(hm) + conv(hB,wms)) -> Ab bf16 + hA fp32[c][s]   (l=3: -> FY in place)
    if (l<3) k_convm<1,2,0,1,1,0><<<1231,256,0,stream>>>(Bb, Wms, bms+l*86, nullptr, Xsc, g2w+l*86, g2b+l*86, st2, nullptr, Ab, hA, nullptr);
    else     k_convm<0,2,0,0,0,1><<<1231,256,0,stream>>>(Bb, Wms, bms+l*86, nullptr, Xsc, g2w+l*86, g2b+l*86, st2, nullptr, nullptr, nullptr, Xsc);
  }

  // GNO MLP weights to bf16 (overlays now-dead FNO buffers)
  k_f2bf<<<(512*96+255)/256,256,0,stream>>>(k1w, w1b, 512*96);
  k_f2bf<<<(256*512+255)/256,256,0,stream>>>(k2w, w2b, 256*512);
  k_f2bf<<<(86*256+255)/256,256,0,stream>>>(k3w, w3b, 86*256);

  for(int ch=0; ch<2; ch++){
    int pair0 = ch*CHUNK_M;
    k_build_kin<<<(CHUNK_M*96)/256,256,0,stream>>>(x_in, nbidx, kinb, pair0);
    k_gemm_mfma<1,1><<<dim3(CHUNK_M/128,4),256,0,stream>>>(kinb, w1b, k1b, (void*)Z1b, CHUNK_M, 512, 96);
    k_gemm_mfma<1,1><<<dim3(CHUNK_M/128,2),256,0,stream>>>(Z1b, w2b, k2b, (void*)Z2b, CHUNK_M, 256, 512);
    k_gemm_mfma<0,0><<<dim3(CHUNK_M/128,1),256,0,stream>>>(Z2b, w3b, k3b, (void*)(K3 + (size_t)pair0*CH), CHUNK_M, 86, 256);
  }

  k_gno_reduce<<<8192,256,0,stream>>>(K3, Xsc, nbidx, nbmsk, p1w, p1b, p2w, p2b, out);
}

// Round 4
// 2205.094 us; speedup vs baseline: 2.9340x; 1.0932x over previous
//
#include <hip/hip_runtime.h>
#include <math.h>

#define CH 86
#define SP 54
#define SS2 2916
#define SS3 157464
#define DG 48
#define MPAD 157568          /* 1231*128 */
#define RT_ROWS (CH*SS2)     /* 250776 rows of (i,x,y) */
#define NSLICE (CH*SP)       /* 4644 */
#define PI_F 3.14159265358979323846f
#define GN_INV (1.0/13541904.0)

static constexpr size_t A512(size_t x){ return (x + 511) & ~((size_t)511); }
static constexpr size_t HB2 = (size_t)CH*SS3*2;               // 27,083,808 (bf16 [c][s])
static constexpr size_t HB4 = (size_t)CH*SS3*4;               // 54,167,616 (fp32 [c][s])
static constexpr size_t AB2 = (size_t)MPAD*96*2;              // 30,253,056 (bf16 [s][96])
static constexpr size_t XB4 = (size_t)MPAD*96*4;              // 60,506,112 (fp32 [s][96])
static constexpr size_t FAB = (size_t)CH*SS2*6*8;             // 12,037,248
static constexpr size_t FBB = (size_t)CH*SP*12*6*8;           // 2,674,944
static constexpr size_t FCB = (size_t)CH*864*8;               // 594,432
static constexpr size_t OFF_HA = 0;                           // hA bf16
static constexpr size_t OFF_HS = OFF_HA + A512(HB2);          // hS fp32
static constexpr size_t OFF_AB = OFF_HS + A512(HB4);
static constexpr size_t OFF_BB = OFF_AB + A512(AB2);
static constexpr size_t OFF_XSC= OFF_BB + A512(AB2);          // hm fp32 [s][96]; becomes FY at l=3
static constexpr size_t OFF_FA = OFF_XSC+ A512(XB4);
static constexpr size_t OFF_FB = OFF_FA + A512(FAB);
static constexpr size_t OFF_FC = OFF_FB + A512(FBB);
static constexpr size_t OFF_FD = OFF_FC + A512(FCB);
static constexpr size_t OFF_FE = OFF_FD + A512(FCB);
static constexpr size_t OFF_ST = OFF_FE + A512(FBB);
static constexpr size_t OFF_WB = OFF_ST + 512;                // 16 conv weights bf16 [96][96]
static constexpr size_t OFF_P1W= OFF_WB + A512((size_t)16*96*96*2);   // p1w bf16 [256][96]
static constexpr size_t OFF_W1 = OFF_P1W+ A512((size_t)256*96*2);
static constexpr size_t OFF_W2 = OFF_W1 + A512((size_t)512*96*2);
static constexpr size_t OFF_W3 = OFF_W2 + A512((size_t)256*512*2);
static constexpr size_t OFF_K3 = OFF_W3 + A512((size_t)86*256*2);     // fp32 [196608][86]
static constexpr size_t OFF_Z2 = OFF_K3 + A512((size_t)196608*CH*4);  // bf16 CHUNK*256
static constexpr size_t OFF_U  = OFF_Z2 + A512((size_t)98304*256*2);  // bf16 8192*96
static constexpr size_t OFF_H1 = OFF_U  + A512((size_t)8192*96*2);    // bf16 8192*256
// GNO big scratch overlays [0..OFF_XSC) (hA/hS/Ab/Bb dead after FNO): kin + Z1
static constexpr int    CHUNK_M = 98304;
static constexpr size_t OFF_KIN = 0;                                  // bf16 CHUNK*96
static constexpr size_t OFF_Z1  = A512((size_t)CHUNK_M*96*2);         // bf16 CHUNK*512

typedef __attribute__((ext_vector_type(8))) short bf16x8;
typedef __attribute__((ext_vector_type(4))) float f32x4;

__device__ __forceinline__ float gelu_f(float x){
  return 0.5f*x*(1.0f + erff(x*0.70710678118654752440f));
}
__device__ __forceinline__ unsigned short f2bf(float x){
  unsigned u = __float_as_uint(x);
  u += 0x7fffu + ((u>>16)&1u);
  return (unsigned short)(u>>16);
}
__device__ __forceinline__ float bf2f(unsigned short u){
  return __uint_as_float(((unsigned)u)<<16);
}

__global__ void k_zero_stats(double* st){ if (threadIdx.x < 16) st[threadIdx.x] = 0.0; }

__global__ __launch_bounds__(256) void k_f2bf(const float* __restrict__ in,
    unsigned short* __restrict__ out, int n)
{
  int i = blockIdx.x*256 + threadIdx.x;
  if (i < n) out[i] = f2bf(in[i]);
}

// conv weight prep: [86][86] fp32 -> [96][96] bf16 zero-padded
__global__ __launch_bounds__(256) void k_wprep(const float* __restrict__ src,
    unsigned short* __restrict__ dst, int slot)
{
  int l = blockIdx.y;
  int idx = blockIdx.x*256 + threadIdx.x;   // 0..9215
  int n = idx/96, k = idx-96*n;
  unsigned short v = 0;
  if (n < 86 && k < 86) v = f2bf(src[(size_t)l*7396 + n*86 + k]);
  dst[(size_t)(l*4+slot)*9216 + idx] = v;
}

// pad [rows][86] fp32 -> [rows][96] bf16
__global__ __launch_bounds__(256) void k_pad_w(const float* __restrict__ src,
    unsigned short* __restrict__ dst, int rows)
{
  int idx = blockIdx.x*256 + threadIdx.x;
  if (idx >= rows*96) return;
  int n = idx/96, k = idx-96*n;
  dst[idx] = (k<86)? f2bf(src[n*86+k]) : (unsigned short)0;
}

// ---------------- lift: writes hA bf16 [c][s] + Ab bf16 [s][96] ----------------
__global__ __launch_bounds__(256) void k_lift(const float* __restrict__ df,
    const float* __restrict__ wl, const float* __restrict__ bl,
    unsigned short* __restrict__ hA, unsigned short* __restrict__ Ab)
{
  __shared__ float vals[128*96];
  const int t = threadIdx.x;
  const int s0 = blockIdx.x*128;
  for(int idx=t; idx<128*96; idx+=256){
    int sl = idx/96, o = idx-96*sl;
    int s = s0+sl;
    float v = 0.f;
    if (o < 86){
      int x = s/2916, r2 = s-2916*x, y = r2/54, z = r2-54*y;
      if (x<DG && y<DG && z<DG){
        int p = (x*DG + y)*DG + z;
        v = wl[o*5]*df[p] + wl[o*5+1]*df[110592+p]
          + wl[o*5+2]*(x*(1.0f/47.0f)) + wl[o*5+3]*(y*(1.0f/47.0f))
          + wl[o*5+4]*(z*(1.0f/47.0f)) + bl[o];
      }
    }
    vals[idx] = v;
  }
  __syncthreads();
  for(int idx=t; idx<128*96; idx+=256)
    Ab[(size_t)s0*96 + idx] = f2bf(vals[idx]);
  for(int idx=t; idx<86*128; idx+=256){
    int c = idx/128, sl = idx-128*c;
    int s = s0+sl;
    if (s < SS3) hA[(size_t)c*SS3 + s] = f2bf(vals[sl*96 + c]);
  }
}

// ---------------- forward partial DFT ----------------
__global__ __launch_bounds__(256) void k_dft_z(const unsigned short* __restrict__ h, float* __restrict__ A)
{
  __shared__ alignas(16) float rows[64*55];
  __shared__ float twc[6*54], tws[6*54];
  const int t = threadIdx.x;
  for(int idx=t; idx<6*54; idx+=256){
    int k = idx/54, z = idx-54*k;
    int m = (k*z)%54;
    float ang = -(2.0f*PI_F/54.0f)*(float)m;
    twc[idx]=cosf(ang); tws[idx]=sinf(ang);
  }
  const int r0 = blockIdx.x*64;
  for(int idx=t; idx<64*54; idx+=256){
    int r = idx/54;
    rows[r*55 + (idx-54*r)] = (r0+r < RT_ROWS)? bf2f(h[(size_t)r0*54 + idx]) : 0.f;
  }
  __syncthreads();
  for(int oi=t; oi<768; oi+=256){
    int r = oi & 63;
    int k = (oi>>6)%6;
    int part = oi/384;
    if (r0+r < RT_ROWS){
      const float* tw = part? tws : twc;
      const float* rp = &rows[r*55];
      const float* twk = &tw[k*54];
      float acc=0.f;
      #pragma unroll 6
      for(int z=0;z<54;z++) acc += rp[z]*twk[z];
      A[((size_t)(r0+r)*6 + k)*2 + part] = acc;
    }
  }
}

__global__ __launch_bounds__(256) void k_dft_y(const float* __restrict__ A, float* __restrict__ B)
{
  __shared__ float asl[4*648];
  __shared__ float twc[12*54], tws[12*54];
  const int t = threadIdx.x;
  for(int idx=t; idx<12*54; idx+=256){
    int kyi = idx/54, y = idx-54*kyi;
    int ky = (kyi<6)? kyi : (42+kyi);
    int m = (ky*y)%54;
    float ang = -(2.0f*PI_F/54.0f)*(float)m;
    twc[idx]=cosf(ang); tws[idx]=sinf(ang);
  }
  const int s0 = blockIdx.x*4;
  for(int idx=t; idx<4*648; idx+=256){
    int sl = idx/648;
    asl[idx] = (s0+sl < NSLICE)? A[(size_t)s0*648 + idx] : 0.f;
  }
  __syncthreads();
  for(int oi=t; oi<4*72; oi+=256){
    int sl = oi/72, o = oi-72*sl;
    if (s0+sl >= NSLICE) continue;
    int kyi = o/6, kz = o-6*kyi;
    const float* base = &asl[sl*648];
    float cr=0.f, ci=0.f;
    for(int y=0;y<54;y++){
      float ar = base[(y*6+kz)*2], ai = base[(y*6+kz)*2+1];
      float tc = twc[kyi*54+y], ts = tws[kyi*54+y];
      cr += ar*tc - ai*ts;
      ci += ar*ts + ai*tc;
    }
    size_t ob = ((size_t)(s0+sl)*12 + kyi)*6 + kz;
    B[ob*2]=cr; B[ob*2+1]=ci;
  }
}

__global__ __launch_bounds__(256) void k_dft_x(const float* __restrict__ B, float* __restrict__ C)
{
  __shared__ float bsl[7776];
  __shared__ float twc[12*54], tws[12*54];
  const int t = threadIdx.x;
  const int i = blockIdx.x;
  for(int idx=t; idx<12*54; idx+=256){
    int kxi = idx/54, x = idx-54*kxi;
    int kx = (kxi<6)? kxi : (42+kxi);
    int m = (kx*x)%54;
    float ang = -(2.0f*PI_F/54.0f)*(float)m;
    twc[idx]=cosf(ang); tws[idx]=sinf(ang);
  }
  for(int idx=t; idx<7776; idx+=256) bsl[idx] = B[(size_t)i*7776 + idx];
  __syncthreads();
  for(int oi=t; oi<864; oi+=256){
    int kxi = oi/72, rest = oi-72*kxi;
    float cr=0.f, ci=0.f;
    for(int x=0;x<54;x++){
      float br = bsl[(x*72+rest)*2], bi = bsl[(x*72+rest)*2+1];
      float tc = twc[kxi*54+x], ts = tws[kxi*54+x];
      cr += br*tc - bi*ts;
      ci += br*ts + bi*tc;
    }
    int kyi = rest/6, kz = rest-6*kyi;
    int c = ((kxi>=6)?2:0) + ((kyi>=6)?1:0);
    int f = ((kxi%6)*6 + (kyi%6))*6 + kz;
    size_t ob = ((size_t)i*4 + c)*216 + f;
    C[ob*2]=cr; C[ob*2+1]=ci;
  }
}

__global__ __launch_bounds__(256) void k_mix(const float* __restrict__ C,
    const float* __restrict__ wr, const float* __restrict__ wi, float* __restrict__ D)
{
  const int f = threadIdx.x;
  if (f >= 216) return;
  const int o = blockIdx.x, c = blockIdx.y;
  const size_t wstride = (size_t)CH*216;
  const float* wrp = wr + ((size_t)c*CH*CH + o)*216 + f;
  const float* wip = wi + ((size_t)c*CH*CH + o)*216 + f;
  const float* cp  = C + ((size_t)c*216 + f)*2;
  float ar=0.f, ai=0.f;
  #pragma unroll 4
  for(int i=0;i<CH;i++){
    float cr = cp[0], cim = cp[1];
    float xr = *wrp, xi = *wip;
    ar += cr*xr - cim*xi;
    ai += cr*xi + cim*xr;
    wrp += wstride; wip += wstride;
    cp += 864*2;
  }
  int mx = f/36, my = (f/6)%6, kz = f%6;
  int kxi = mx + ((c>=2)?6:0);
  int kyi = my + ((c&1)?6:0);
  size_t ob = (((size_t)o*12 + kxi)*12 + kyi)*6 + kz;
  D[ob*2]=ar; D[ob*2+1]=ai;
}

// ---------------- inverse partial DFT ----------------
__global__ __launch_bounds__(256) void k_idft_x(const float* __restrict__ D, float* __restrict__ E)
{
  __shared__ float dsl[1728];
  __shared__ float twc[12*54], tws[12*54];
  const int t = threadIdx.x;
  const int o = blockIdx.x;
  for(int idx=t; idx<12*54; idx+=256){
    int kxi = idx/54, x = idx-54*kxi;
    int kx = (kxi<6)? kxi : (42+kxi);
    int m = (kx*x)%54;
    float ang = (2.0f*PI_F/54.0f)*(float)m;
    twc[idx]=cosf(ang); tws[idx]=sinf(ang);
  }
  for(int idx=t; idx<1728; idx+=256) dsl[idx] = D[(size_t)o*1728 + idx];
  __syncthreads();
  for(int oi=t; oi<3888; oi+=256){
    int x = oi/72, rest = oi-72*x;
    float er=0.f, ei=0.f;
    #pragma unroll
    for(int kxi=0;kxi<12;kxi++){
      float dr = dsl[(kxi*72+rest)*2], di = dsl[(kxi*72+rest)*2+1];
      float tc = twc[kxi*54+x], ts = tws[kxi*54+x];
      er += dr*tc - di*ts;
      ei += dr*ts + di*tc;
    }
    size_t ob = (size_t)o*3888 + oi;
    E[ob*2]=er; E[ob*2+1]=ei;
  }
}

__global__ __launch_bounds__(256) void k_idft_y(const float* __restrict__ E, float* __restrict__ F)
{
  __shared__ float esl[4*144];
  __shared__ float twc[12*54], tws[12*54];
  const int t = threadIdx.x;
  for(int idx=t; idx<12*54; idx+=256){
    int kyi = idx/54, y = idx-54*kyi;
    int ky = (kyi<6)? kyi : (42+kyi);
    int m = (ky*y)%54;
    float ang = (2.0f*PI_F/54.0f)*(float)m;
    twc[idx]=cosf(ang); tws[idx]=sinf(ang);
  }
  const int s0 = blockIdx.x*4;
  for(int idx=t; idx<4*144; idx+=256){
    int sl = idx/144;
    esl[idx] = (s0+sl < NSLICE)? E[(size_t)s0*144 + idx] : 0.f;
  }
  __syncthreads();
  for(int oi=t; oi<4*324; oi+=256){
    int sl = oi/324, rest = oi-324*sl;
    if (s0+sl >= NSLICE) continue;
    int y = rest/6, kz = rest-6*y;
    const float* base = &esl[sl*144];
    float fr=0.f, fi=0.f;
    #pragma unroll
    for(int kyi=0;kyi<12;kyi++){
      float er = base[(kyi*6+kz)*2], ei = base[(kyi*6+kz)*2+1];
      float tc = twc[kyi*54+y], ts = tws[kyi*54+y];
      fr += er*tc - ei*ts;
      fi += er*ts + ei*tc;
    }
    size_t ob = ((size_t)(s0+sl)*54 + y)*6 + kz;
    F[ob*2]=fr; F[ob*2+1]=fi;
  }
}

__global__ __launch_bounds__(256) void k_idft_z(const float* __restrict__ F,
    float* __restrict__ hs, double* __restrict__ st)
{
  __shared__ float rws[64*12];
  __shared__ float twc[5*54], tws[5*54];
  __shared__ float red[8];
  const int t = threadIdx.x;
  for(int idx=t; idx<5*54; idx+=256){
    int k = idx/54 + 1, z = idx%54;
    int m = (k*z)%54;
    float ang = (2.0f*PI_F/54.0f)*(float)m;
    twc[idx]=cosf(ang); tws[idx]=sinf(ang);
  }
  const int r0 = blockIdx.x*64;
  for(int idx=t; idx<768; idx+=256){
    int r = idx/12;
    rws[idx] = (r0+r < RT_ROWS)? F[(size_t)r0*12 + idx] : 0.f;
  }
  __syncthreads();
  const float inv = 1.0f/157464.0f;
  float lsum=0.f, lsq=0.f;
  for(int oi=t; oi<64*54; oi+=256){
    int r = oi/54, z = oi-54*r;
    if (r0+r < RT_ROWS){
      const float* fr = &rws[r*12];
      float acc = fr[0];
      #pragma unroll
      for(int k=1;k<=5;k++)
        acc += 2.0f*(fr[2*k]*twc[(k-1)*54+z] - fr[2*k+1]*tws[(k-1)*54+z]);
      acc *= inv;
      hs[(size_t)r0*54 + oi] = acc;
      lsum += acc; lsq += acc*acc;
    }
  }
  #pragma unroll
  for(int off=32; off; off>>=1){
    lsum += __shfl_down(lsum, off, 64);
    lsq  += __shfl_down(lsq,  off, 64);
  }
  if ((t&63)==0){ red[(t>>6)*2]=lsum; red[(t>>6)*2+1]=lsq; }
  __syncthreads();
  if (t==0){
    double s1 = (double)red[0]+red[2]+red[4]+red[6];
    double s2 = (double)red[1]+red[3]+red[5]+red[7];
    atomicAdd(st, s1); atomicAdd(st+1, s2);
  }
}

// ---------------- fused skip + m1 + m2 (per 128-row tile) ----------------
// P1: Bb = act1(gn1(hS) + Ab@Wskip + bskip)  -> global + LDS T-tile
// P2: T = gelu(Bb@Wm1 + m1b)                 -> LDS (per-wave private rows)
// P3: hm = T@Wm2 + m2b                       -> Xsc fp32 + stats
template<int ACT1>
__global__ __launch_bounds__(256) void k_fuse3(
    const unsigned short* __restrict__ Ain, const unsigned short* __restrict__ Wl3,
    const float* __restrict__ bsk, const float* __restrict__ b1,
    const float* __restrict__ b2,
    const float* __restrict__ hS, const float* __restrict__ g1,
    const float* __restrict__ bg1, const double* __restrict__ st1,
    double* __restrict__ st2,
    unsigned short* __restrict__ Bb, float* __restrict__ Hm)
{
  __shared__ unsigned short Wl[96*96];
  __shared__ unsigned short Achunk[8*512];
  __shared__ unsigned short Tt[128*96];
  __shared__ float red[8];
  const int t = threadIdx.x, lane = t&63, w = t>>6;
  const int m0 = blockIdx.x*128;
  const int lr = lane>>2, lq = lane&3;
  const int colb = lane&15, rowq = (lane>>4)*4;
  f32x4 acc[2][6];

  // ---- P1: stage Wskip
  for(int s=w; s<18; s+=4){
    const unsigned short* gw = Wl3 + s*512 + lane*8;
    __builtin_amdgcn_global_load_lds((const __attribute__((address_space(1))) void*)gw,
        (__attribute__((address_space(3))) void*)&Wl[s*512], 16, 0, 0);
  }
  #pragma unroll
  for(int s=0;s<2;s++)
    #pragma unroll
    for(int n=0;n<6;n++) acc[s][n] = (f32x4){0.f,0.f,0.f,0.f};
  #pragma unroll
  for(int k0=0;k0<96;k0+=32){
    __syncthreads();
    #pragma unroll
    for(int j=0;j<2;j++){
      int slot = w*2+j;
      int row = slot*16 + lr;
      const unsigned short* ga = Ain + (size_t)(m0+row)*96 + k0 + lq*8;
      __builtin_amdgcn_global_load_lds((const __attribute__((address_space(1))) void*)ga,
          (__attribute__((address_space(3))) void*)&Achunk[slot*512], 16, 0, 0);
    }
    __syncthreads();
    bf16x8 af[2], bf[6];
    #pragma unroll
    for(int s=0;s<2;s++)
      af[s] = *(const bf16x8*)&Achunk[(w*32 + s*16 + (lane&15))*32 + (lane>>4)*8];
    #pragma unroll
    for(int n=0;n<6;n++)
      bf[n] = *(const bf16x8*)&Wl[(n*16 + (lane&15))*96 + k0 + (lane>>4)*8];
    #pragma unroll
    for(int s=0;s<2;s++)
      #pragma unroll
      for(int n=0;n<6;n++)
        acc[s][n] = __builtin_amdgcn_mfma_f32_16x16x32_bf16(af[s], bf[n], acc[s][n], 0, 0, 0);
  }
  {
    double m = st1[0]*GN_INV;
    double va = st1[1]*GN_INV - m*m;
    float mu = (float)m, rs = (float)(1.0/sqrt(va + 1e-5));
    #pragma unroll
    for(int n=0;n<6;n++){
      int col = n*16 + colb;
      bool cv = (col < CH);
      float bn=0.f, gg=1.f, bb=0.f;
      if (cv){ bn = bsk[col]; gg = g1[col]; bb = bg1[col]; }
      #pragma unroll
      for(int s=0;s<2;s++){
        #pragma unroll
        for(int r=0;r<4;r++){
          int rowl = w*32 + s*16 + rowq + r;
          int row = m0 + rowl;
          float v = 0.f;
          if (cv){
            v = acc[s][n][r] + bn;
            if (row < SS3) v += (hS[(size_t)col*SS3 + row]-mu)*rs*gg + bb;
            if (ACT1) v = gelu_f(v);
          }
          unsigned short vb = f2bf(v);
          Bb[(size_t)row*96 + col] = vb;
          Tt[rowl*96 + col] = vb;
        }
      }
    }
  }

  // ---- P2: m1 (A from own-wave T rows, no global staging)
  __syncthreads();
  for(int s=w; s<18; s+=4){
    const unsigned short* gw = Wl3 + 9216 + s*512 + lane*8;
    __builtin_amdgcn_global_load_lds((const __attribute__((address_space(1))) void*)gw,
        (__attribute__((address_space(3))) void*)&Wl[s*512], 16, 0, 0);
  }
  #pragma unroll
  for(int s=0;s<2;s++)
    #pragma unroll
    for(int n=0;n<6;n++) acc[s][n] = (f32x4){0.f,0.f,0.f,0.f};
  __syncthreads();
  #pragma unroll
  for(int k0=0;k0<96;k0+=32){
    bf16x8 af[2], bf[6];
    #pragma unroll
    for(int s=0;s<2;s++)
      af[s] = *(const bf16x8*)&Tt[(w*32 + s*16 + (lane&15))*96 + k0 + (lane>>4)*8];
    #pragma unroll
    for(int n=0;n<6;n++)
      bf[n] = *(const bf16x8*)&Wl[(n*16 + (lane&15))*96 + k0 + (lane>>4)*8];
    #pragma unroll
    for(int s=0;s<2;s++)
      #pragma unroll
      for(int n=0;n<6;n++)
        acc[s][n] = __builtin_amdgcn_mfma_f32_16x16x32_bf16(af[s], bf[n], acc[s][n], 0, 0, 0);
  }
  #pragma unroll
  for(int n=0;n<6;n++){
    int col = n*16 + colb;
    bool cv = (col < CH);
    float bn = cv? b1[col] : 0.f;
    #pragma unroll
    for(int s=0;s<2;s++){
      #pragma unroll
      for(int r=0;r<4;r++){
        int rowl = w*32 + s*16 + rowq + r;
        float v = cv? gelu_f(acc[s][n][r] + bn) : 0.f;
        Tt[rowl*96 + col] = f2bf(v);
      }
    }
  }

  // ---- P3: m2
  __syncthreads();
  for(int s=w; s<18; s+=4){
    const unsigned short* gw = Wl3 + 18432 + s*512 + lane*8;
    __builtin_amdgcn_global_load_lds((const __attribute__((address_space(1))) void*)gw,
        (__attribute__((address_space(3))) void*)&Wl[s*512], 16, 0, 0);
  }
  #pragma unroll
  for(int s=0;s<2;s++)
    #pragma unroll
    for(int n=0;n<6;n++) acc[s][n] = (f32x4){0.f,0.f,0.f,0.f};
  __syncthreads();
  #pragma unroll
  for(int k0=0;k0<96;k0+=32){
    bf16x8 af[2], bf[6];
    #pragma unroll
    for(int s=0;s<2;s++)
      af[s] = *(const bf16x8*)&Tt[(w*32 + s*16 + (lane&15))*96 + k0 + (lane>>4)*8];
    #pragma unroll
    for(int n=0;n<6;n++)
      bf[n] = *(const bf16x8*)&Wl[(n*16 + (lane&15))*96 + k0 + (lane>>4)*8];
    #pragma unroll
    for(int s=0;s<2;s++)
      #pragma unroll
      for(int n=0;n<6;n++)
        acc[s][n] = __builtin_amdgcn_mfma_f32_16x16x32_bf16(af[s], bf[n], acc[s][n], 0, 0, 0);
  }
  float lsum=0.f, lsq=0.f;
  #pragma unroll
  for(int n=0;n<6;n++){
    int col = n*16 + colb;
    bool cv = (col < CH);
    float bn = cv? b2[col] : 0.f;
    #pragma unroll
    for(int s=0;s<2;s++){
      #pragma unroll
      for(int r=0;r<4;r++){
        int row = m0 + w*32 + s*16 + rowq + r;
        float v = 0.f;
        if (cv){
          v = acc[s][n][r] + bn;
          if (row < SS3){ lsum += v; lsq += v*v; }
        }
        Hm[(size_t)row*96 + col] = v;
      }
    }
  }
  #pragma unroll
  for(int off=32; off; off>>=1){
    lsum += __shfl_down(lsum, off, 64);
    lsq  += __shfl_down(lsq,  off, 64);
  }
  if (lane==0){ red[w*2]=lsum; red[w*2+1]=lsq; }
  __syncthreads();
  if (t==0){
    double s1 = (double)red[0]+red[2]+red[4]+red[6];
    double s2 = (double)red[1]+red[3]+red[5]+red[7];
    atomicAdd(st2, s1); atomicAdd(st2+1, s2);
  }
}

// ---------------- ms conv + gn2 combine: h = act(gn2(Hm) + Bb@Wms + bms) ----------------
// LAST=0: write Ab bf16 [s][96] + hA bf16 [c][s]; LAST=1: write FY fp32 [s][96] (in place over Hm)
template<int LAST>
__global__ __launch_bounds__(256) void k_convms(
    const unsigned short* __restrict__ Ain, const unsigned short* __restrict__ Wm,
    const float* __restrict__ bms,
    const float* __restrict__ Hm, const float* __restrict__ g2,
    const float* __restrict__ bg2, const double* __restrict__ st2,
    unsigned short* __restrict__ Ab, unsigned short* __restrict__ hA,
    float* __restrict__ FY)
{
  __shared__ unsigned short Wl[96*96];
  __shared__ unsigned short Achunk[8*512];
  const int t = threadIdx.x, lane = t&63, w = t>>6;
  const int m0 = blockIdx.x*128;
  const int lr = lane>>2, lq = lane&3;
  for(int s=w; s<18; s+=4){
    const unsigned short* gw = Wm + s*512 + lane*8;
    __builtin_amdgcn_global_load_lds((const __attribute__((address_space(1))) void*)gw,
        (__attribute__((address_space(3))) void*)&Wl[s*512], 16, 0, 0);
  }
  f32x4 acc[2][6];
  #pragma unroll
  for(int s=0;s<2;s++)
    #pragma unroll
    for(int n=0;n<6;n++) acc[s][n] = (f32x4){0.f,0.f,0.f,0.f};
  #pragma unroll
  for(int k0=0;k0<96;k0+=32){
    __syncthreads();
    #pragma unroll
    for(int j=0;j<2;j++){
      int slot = w*2+j;
      int row = slot*16 + lr;
      const unsigned short* ga = Ain + (size_t)(m0+row)*96 + k0 + lq*8;
      __builtin_amdgcn_global_load_lds((const __attribute__((address_space(1))) void*)ga,
          (__attribute__((address_space(3))) void*)&Achunk[slot*512], 16, 0, 0);
    }
    __syncthreads();
    bf16x8 af[2], bf[6];
    #pragma unroll
    for(int s=0;s<2;s++)
      af[s] = *(const bf16x8*)&Achunk[(w*32 + s*16 + (lane&15))*32 + (lane>>4)*8];
    #pragma unroll
    for(int n=0;n<6;n++)
      bf[n] = *(const bf16x8*)&Wl[(n*16 + (lane&15))*96 + k0 + (lane>>4)*8];
    #pragma unroll
    for(int s=0;s<2;s++)
      #pragma unroll
      for(int n=0;n<6;n++)
        acc[s][n] = __builtin_amdgcn_mfma_f32_16x16x32_bf16(af[s], bf[n], acc[s][n], 0, 0, 0);
  }
  double m = st2[0]*GN_INV;
  double va = st2[1]*GN_INV - m*m;
  float mu = (float)m, rs = (float)(1.0/sqrt(va + 1e-5));
  const int colb = lane&15, rowq = (lane>>4)*4;
  #pragma unroll
  for(int n=0;n<6;n++){
    int col = n*16 + colb;
    bool cv = (col < CH);
    float bn=0.f, gg=1.f, bb=0.f;
    if (cv){ bn = bms[col]; gg = g2[col]; bb = bg2[col]; }
    #pragma unroll
    for(int s=0;s<2;s++){
      #pragma unroll
      for(int r=0;r<4;r++){
        int row = m0 + w*32 + s*16 + rowq + r;
        float v = 0.f;
        if (cv){
          v = acc[s][n][r] + bn + (Hm[(size_t)row*96 + col]-mu)*rs*gg + bb;
          if (!LAST) v = gelu_f(v);
        }
        if (LAST){
          FY[(size_t)row*96 + col] = v;
        } else {
          Ab[(size_t)row*96 + col] = f2bf(v);
          if (cv && row < SS3) hA[(size_t)col*SS3 + row] = f2bf(v);
        }
      }
    }
  }
}

// ---------------- kin: [pair][96] bf16 = [y-embed(48) | q-embed(48)] ----------------
__global__ __launch_bounds__(256) void k_build_kin(const float* __restrict__ x_in,
    const int* __restrict__ nb_idx, unsigned short* __restrict__ kin, int pair0)
{
  int gidx = blockIdx.x*256 + threadIdx.x;
  int lp = gidx/96, col = gidx - lp*96;
  int pair = pair0 + lp;
  int qi = pair/24;
  int cc = col; bool isq = false;
  if (cc >= 48){ cc -= 48; isq = true; }
  int ci = cc>>4, e = cc&15;
  int f = e&7; bool is_sin = (e>=8);
  float coord;
  if (isq){
    coord = x_in[qi*3 + ci];
  } else {
    int pt = nb_idx[pair];
    int gcoord;
    if (ci==0) gcoord = pt/2304;
    else if (ci==1) gcoord = (pt/48)%48;
    else gcoord = pt%48;
    coord = gcoord*(1.0f/47.0f);
  }
  float freq = exp2f(-(float)f * 1.66096404744368117f);  // 10000^{-f/8}
  float ang = coord*freq;
  kin[gidx] = f2bf(is_sin ? sinf(ang) : cosf(ang));
}

// ---------------- MFMA GEMM: C[m][n] = act(sum_k A[m][k]*B[n][k] + bias[n]) ----------------
template<int ACT, int OUT_BF16>
__global__ __launch_bounds__(256,2) void k_gemm_mfma(
    const unsigned short* __restrict__ A, const unsigned short* __restrict__ B,
    const float* __restrict__ bias, void* __restrict__ Cout,
    int M, int N, int K)
{
  __shared__ unsigned short As[128*32];
  __shared__ unsigned short Bs[128*32];
  const int t = threadIdx.x;
  const int lane = t & 63, w = t >> 6;
  const int wm = w >> 1, wn = w & 1;
  const int m0 = blockIdx.x*128, n0 = blockIdx.y*128;
  const int lr = lane >> 2, lq = lane & 3;
  f32x4 acc[4][4];
  #pragma unroll
  for(int s=0;s<4;s++)
    #pragma unroll
    for(int n=0;n<4;n++) acc[s][n] = (f32x4){0.f,0.f,0.f,0.f};

  for(int k0=0;k0<K;k0+=32){
    __syncthreads();
    #pragma unroll
    for(int j=0;j<2;j++){
      int slot = w*2 + j;
      int row = slot*16 + lr;
      const unsigned short* ga = A + (size_t)(m0+row)*K + k0 + lq*8;
      __builtin_amdgcn_global_load_lds((const __attribute__((address_space(1))) void*)ga,
          (__attribute__((address_space(3))) void*)&As[slot*512], 16, 0, 0);
      int brow = n0 + row; if (brow > N-1) brow = N-1;
      const unsigned short* gb = B + (size_t)brow*K + k0 + lq*8;
      __builtin_amdgcn_global_load_lds((const __attribute__((address_space(1))) void*)gb,
          (__attribute__((address_space(3))) void*)&Bs[slot*512], 16, 0, 0);
    }
    __syncthreads();
    bf16x8 af[4], bg[4];
    #pragma unroll
    for(int s=0;s<4;s++)
      af[s] = *(const bf16x8*)&As[(wm*64 + s*16 + (lane&15))*32 + (lane>>4)*8];
    #pragma unroll
    for(int n=0;n<4;n++)
      bg[n] = *(const bf16x8*)&Bs[(wn*64 + n*16 + (lane&15))*32 + (lane>>4)*8];
    #pragma unroll
    for(int s=0;s<4;s++)
      #pragma unroll
      for(int n=0;n<4;n++)
        acc[s][n] = __builtin_amdgcn_mfma_f32_16x16x32_bf16(af[s], bg[n], acc[s][n], 0, 0, 0);
  }

  unsigned short* Cb = (unsigned short*)Cout;
  float* Cf = (float*)Cout;
  const int colb = n0 + wn*64 + (lane&15);
  const int rowb = m0 + wm*64 + (lane>>4)*4;
  #pragma unroll
  for(int n=0;n<4;n++){
    int col = colb + n*16;
    if (col < N){
      float bn = bias[col];
      #pragma unroll
      for(int s=0;s<4;s++){
        int row = rowb + s*16;
        #pragma unroll
        for(int r=0;r<4;r++){
          float v = acc[s][n][r] + bn;
          if (ACT) v = gelu_f(v);
          if (OUT_BF16) Cb[(size_t)(row+r)*N + col] = f2bf(v);
          else          Cf[(size_t)(row+r)*N + col] = v;
        }
      }
    }
  }
}

// ---------------- GNO masked reduce -> U[8192][96] bf16 (one wave per query) ------------
__global__ __launch_bounds__(256) void k_gno_u(
    const float* __restrict__ K3, const float* __restrict__ FY,
    const int* __restrict__ nb_idx, const int* __restrict__ nb_mask,
    unsigned short* __restrict__ U)
{
  __shared__ int sidx[4][24];
  __shared__ float smk[4][24];
  const int t = threadIdx.x, w = t>>6, lane = t&63;
  const int i0 = blockIdx.x*4;
  if (t < 96){
    int q = t/24, k = t-24*q;
    int pt = nb_idx[(i0+q)*24+k];
    int x = pt/2304, rem = pt-2304*x, y = rem/48, z = rem-48*y;
    sidx[q][k] = x*2916 + y*54 + z;
    smk[q][k] = (nb_mask[(i0+q)*24+k] != 0)? 1.f : 0.f;
  }
  __syncthreads();
  const int i = i0 + w;
  const int c1 = lane, c2 = 64+lane;
  float a1=0.f, a2=0.f, den=0.f;
  for(int k=0;k<24;k++){
    float mk = smk[w][k];
    den += mk;
    if (mk > 0.f){
      const float* k3p = K3 + (size_t)(i*24+k)*CH;
      const float* fyp = FY + (size_t)sidx[w][k]*96;
      a1 += k3p[c1]*fyp[c1];
      if (c2 < CH) a2 += k3p[c2]*fyp[c2];
    }
  }
  if (den < 1.f) den = 1.f;
  U[(size_t)i*96 + c1] = f2bf(a1/den);
  if (c2 < 96) U[(size_t)i*96 + c2] = f2bf((c2 < CH)? a2/den : 0.f);
}

// ---------------- final dot: out[i] = H1[i]·p2w + p2b ----------------
__global__ __launch_bounds__(256) void k_out(const unsigned short* __restrict__ H1,
    const float* __restrict__ p2w, const float* __restrict__ p2b,
    float* __restrict__ out)
{
  const int t = threadIdx.x, w = t>>6, lane = t&63;
  const int i = blockIdx.x*4 + w;
  const unsigned short* hp = H1 + (size_t)i*256 + lane*4;
  float s = 0.f;
  #pragma unroll
  for(int j=0;j<4;j++) s += bf2f(hp[j]) * p2w[lane*4+j];
  #pragma unroll
  for(int off=32; off; off>>=1) s += __shfl_down(s, off, 64);
  if (lane==0) out[i] = s + p2b[0];
}

// ---------------- launch ----------------
extern "C" void kernel_launch(void* const* d_in, const int* in_sizes, int n_in,
                              void* d_out, int out_size, void* d_ws, size_t ws_size,
                              hipStream_t stream)
{
  (void)in_sizes; (void)n_in; (void)out_size; (void)ws_size;
  const float* x_in  = (const float*)d_in[0];
  const float* df    = (const float*)d_in[2];
  const int*   nbidx = (const int*)d_in[3];
  const int*   nbmsk = (const int*)d_in[4];
  const float* wlift = (const float*)d_in[5];
  const float* blift = (const float*)d_in[6];
  const float* spwr  = (const float*)d_in[7];
  const float* spwi  = (const float*)d_in[8];
  const float* wskip = (const float*)d_in[9];
  const float* bskip = (const float*)d_in[10];
  const float* m1w   = (const float*)d_in[11];
  const float* m1b   = (const float*)d_in[12];
  const float* m2w   = (const float*)d_in[13];
  const float* m2b   = (const float*)d_in[14];
  const float* wms   = (const float*)d_in[15];
  const float* bms   = (const float*)d_in[16];
  const float* g1w   = (const float*)d_in[17];
  const float* g1b   = (const float*)d_in[18];
  const float* g2w   = (const float*)d_in[19];
  const float* g2b   = (const float*)d_in[20];
  const float* k1w   = (const float*)d_in[21];
  const float* k1b   = (const float*)d_in[22];
  const float* k2w   = (const float*)d_in[23];
  const float* k2b   = (const float*)d_in[24];
  const float* k3w   = (const float*)d_in[25];
  const float* k3b   = (const float*)d_in[26];
  const float* p1w   = (const float*)d_in[27];
  const float* p1b   = (const float*)d_in[28];
  const float* p2w   = (const float*)d_in[29];
  const float* p2b   = (const float*)d_in[30];
  float* out = (float*)d_out;
  char* ws = (char*)d_ws;

  unsigned short* hAb = (unsigned short*)(ws + OFF_HA);
  float* hS = (float*)(ws + OFF_HS);
  unsigned short* Ab = (unsigned short*)(ws + OFF_AB);
  unsigned short* Bb = (unsigned short*)(ws + OFF_BB);
  float* Xsc = (float*)(ws + OFF_XSC);
  float* fA = (float*)(ws + OFF_FA);
  float* fB = (float*)(ws + OFF_FB);
  float* fC = (float*)(ws + OFF_FC);
  float* fD = (float*)(ws + OFF_FD);
  float* fE = (float*)(ws + OFF_FE);
  double* st= (double*)(ws + OFF_ST);
  unsigned short* Wb = (unsigned short*)(ws + OFF_WB);
  unsigned short* p1wb = (unsigned short*)(ws + OFF_P1W);
  unsigned short* w1b  = (unsigned short*)(ws + OFF_W1);
  unsigned short* w2b  = (unsigned short*)(ws + OFF_W2);
  unsigned short* w3b  = (unsigned short*)(ws + OFF_W3);
  float* K3 = (float*)(ws + OFF_K3);
  unsigned short* Z2b  = (unsigned short*)(ws + OFF_Z2);
  unsigned short* Ub   = (unsigned short*)(ws + OFF_U);
  unsigned short* H1b  = (unsigned short*)(ws + OFF_H1);
  unsigned short* kinb = (unsigned short*)(ws + OFF_KIN);
  unsigned short* Z1b  = (unsigned short*)(ws + OFF_Z1);

  k_zero_stats<<<1,64,0,stream>>>(st);
  k_wprep<<<dim3(36,4),256,0,stream>>>(wskip, Wb, 0);
  k_wprep<<<dim3(36,4),256,0,stream>>>(m1w,   Wb, 1);
  k_wprep<<<dim3(36,4),256,0,stream>>>(m2w,   Wb, 2);
  k_wprep<<<dim3(36,4),256,0,stream>>>(wms,   Wb, 3);
  k_pad_w<<<96,256,0,stream>>>(p1w, p1wb, 256);
  k_f2bf<<<(512*96+255)/256,256,0,stream>>>(k1w, w1b, 512*96);
  k_f2bf<<<(256*512+255)/256,256,0,stream>>>(k2w, w2b, 256*512);
  k_f2bf<<<(86*256+255)/256,256,0,stream>>>(k3w, w3b, 86*256);
  k_lift<<<1231,256,0,stream>>>(df, wlift, blift, hAb, Ab);

  for(int l=0;l<4;l++){
    const float* wr_l = spwr + (size_t)l*4*CH*CH*216;
    const float* wi_l = spwi + (size_t)l*4*CH*CH*216;
    double* st1 = st + l*4;
    double* st2 = st + l*4 + 2;
    k_dft_z<<<3919,256,0,stream>>>(hAb, fA);
    k_dft_y<<<1161,256,0,stream>>>(fA, fB);
    k_dft_x<<<86,256,0,stream>>>(fB, fC);
    k_mix<<<dim3(86,4),256,0,stream>>>(fC, wr_l, wi_l, fD);
    k_idft_x<<<86,256,0,stream>>>(fD, fE);
    k_idft_y<<<1161,256,0,stream>>>(fE, fA);
    k_idft_z<<<3919,256,0,stream>>>(fA, hS, st1);
    const unsigned short* Wl3 = Wb + (size_t)l*4*9216;
    const unsigned short* Wms = Wb + (size_t)(l*4+3)*9216;
    if (l<3){
      k_fuse3<1><<<1231,256,0,stream>>>(Ab, Wl3, bskip+l*86, m1b+l*86, m2b+l*86,
          hS, g1w+l*86, g1b+l*86, st1, st2, Bb, Xsc);
      k_convms<0><<<1231,256,0,stream>>>(Bb, Wms, bms+l*86, Xsc, g2w+l*86, g2b+l*86,
          st2, Ab, hAb, nullptr);
    } else {
      k_fuse3<0><<<1231,256,0,stream>>>(Ab, Wl3, bskip+l*86, m1b+l*86, m2b+l*86,
          hS, g1w+l*86, g1b+l*86, st1, st2, Bb, Xsc);
      k_convms<1><<<1231,256,0,stream>>>(Bb, Wms, bms+l*86, Xsc, g2w+l*86, g2b+l*86,
          st2, nullptr, nullptr, Xsc);
    }
  }

  for(int ch=0; ch<2; ch++){
    int pair0 = ch*CHUNK_M;
    k_build_kin<<<(CHUNK_M*96)/256,256,0,stream>>>(x_in, nbidx, kinb, pair0);
    k_gemm_mfma<1,1><<<dim3(CHUNK_M/128,4),256,0,stream>>>(kinb, w1b, k1b, (void*)Z1b, CHUNK_M, 512, 96);
    k_gemm_mfma<1,1><<<dim3(CHUNK_M/128,2),256,0,stream>>>(Z1b, w2b, k2b, (void*)Z2b, CHUNK_M, 256, 512);
    k_gemm_mfma<0,0><<<dim3(CHUNK_M/128,1),256,0,stream>>>(Z2b, w3b, k3b, (void*)(K3 + (size_t)pair0*CH), CHUNK_M, 86, 256);
  }

  k_gno_u<<<2048,256,0,stream>>>(K3, Xsc, nbidx, nbmsk, Ub);
  k_gemm_mfma<1,1><<<dim3(64,2),256,0,stream>>>(Ub, p1wb, p1b, (void*)H1b, 8192, 256, 96);
  k_out<<<2048,256,0,stream>>>(H1b, p2w, p2b, out);
}